// Round 3
// baseline (6603.235 us; speedup 1.0000x reference)
//
#include <hip/hip_runtime.h>
#include <hip/hip_bf16.h>

// ---------------------------------------------------------------------------
// TransformerEncoder: B=2, S=2048, D=512, H=8, DH=64, DF=2048, NX=6 layers
// I/O dtype: FP32 (inputs and output) — established from npz sizes in r2.
// Internals: bf16 activations for MFMA GEMMs, fp32 residual stream + LN.
// ---------------------------------------------------------------------------

typedef __attribute__((ext_vector_type(4))) float  floatx4;
typedef __attribute__((ext_vector_type(8))) short  short8;
typedef __attribute__((ext_vector_type(4))) short  short4_t;
typedef __bf16 bf16x8 __attribute__((ext_vector_type(8)));

#define SS 2048
#define DD 512
#define HH 8
#define DHH 64
#define NROWS 4096   /* B*S */

__device__ __forceinline__ float bf2f(unsigned short u) {
    union { float f; unsigned int i; } x; x.i = ((unsigned int)u) << 16; return x.f;
}
__device__ __forceinline__ unsigned short f2bf(float f) {
    union { float f; unsigned int i; } x; x.f = f;
    unsigned int lsb = (x.i >> 16) & 1u;
    x.i += 0x7fffu + lsb;               // round-to-nearest-even
    return (unsigned short)(x.i >> 16);
}

#if __has_builtin(__builtin_amdgcn_mfma_f32_16x16x32_bf16)
__device__ __forceinline__ void mfma16x16x32(floatx4& d, short8 a, short8 b) {
    bf16x8 ab, bb;
    __builtin_memcpy(&ab, &a, 16);
    __builtin_memcpy(&bb, &b, 16);
    d = __builtin_amdgcn_mfma_f32_16x16x32_bf16(ab, bb, d, 0, 0, 0);
}
#else
__device__ __forceinline__ void mfma16x16x32(floatx4& d, short8 a, short8 b) {
    asm volatile("s_nop 1\n\t"
                 "v_mfma_f32_16x16x32_bf16 %0, %1, %2, %0\n\t"
                 "s_nop 7\n\t"
                 "s_nop 7"
                 : "+v"(d) : "v"(a), "v"(b));
}
#endif

// ---------------------------------------------------------------------------
// Weight transpose + fp32->bf16: W [z][R][C] fp32 -> WT [z][C][R] bf16
// ---------------------------------------------------------------------------
__global__ __launch_bounds__(256) void transpose_k(const float* __restrict__ W,
                                                   ushort* __restrict__ WT,
                                                   int R, int C) {
    __shared__ ushort t[32][33];
    int z = blockIdx.z;
    const float* Wz = W + (size_t)z * R * C;
    ushort* WTz = WT + (size_t)z * R * C;
    int c0 = blockIdx.x * 32, r0 = blockIdx.y * 32;
    int x = threadIdx.x, y = threadIdx.y;         // (32,8)
#pragma unroll
    for (int i = 0; i < 32; i += 8)
        t[y + i][x] = f2bf(Wz[(size_t)(r0 + y + i) * C + c0 + x]);
    __syncthreads();
#pragma unroll
    for (int i = 0; i < 32; i += 8)
        WTz[(size_t)(c0 + y + i) * R + r0 + x] = t[x][y + i];
}

// ---------------------------------------------------------------------------
// Embedding + positional encoding.  pe[s][c] = sin/cos(s * 10000^(-c/256))
// (even c -> sin, odd c -> cos; exponent c/256 for both — faithful to ref)
// ---------------------------------------------------------------------------
__global__ __launch_bounds__(256) void embed_pe(const int* __restrict__ x,
                                                const float* __restrict__ emb,
                                                float* __restrict__ h,
                                                ushort* __restrict__ hb) {
    __shared__ int isI32;
    int row = blockIdx.x, tid = threadIdx.x;
    if (tid == 0) isI32 = 0;
    __syncthreads();
    // int64-vs-int32 layout probe: odd 32-bit words of first 2048 pairs.
    int acc = 0;
    for (int i = tid; i < 2048; i += 256) acc |= x[2 * i + 1];
    if (acc) isI32 = 1;
    __syncthreads();
    int tok = isI32 ? x[row] : x[2 * row];
    int s = row & (SS - 1);
    const float* er = emb + (size_t)tok * DD;
    for (int c = tid; c < DD; c += 256) {
        float e = er[c] * 22.62741699796952f;              // sqrt(512)
        float freq = __expf(-((float)c * (1.f / 256.f)) * 9.210340371976184f); // ln(1e4)
        float ang = (float)s * freq;
        float pe = (c & 1) ? cosf(ang) : sinf(ang);
        float val = e + pe;
        h[(size_t)row * DD + c] = val;
        hb[(size_t)row * DD + c] = f2bf(val);
    }
}

// ---------------------------------------------------------------------------
// GEMM: C[M,N] = A[M,K] @ B[K,N] + bias, B supplied TRANSPOSED (BT[N,K], bf16).
// 64x64 tile, BK=32, 256 threads = 4 waves, each wave 16 rows x 64 cols.
// MFMA 16x16x32 bf16; fp32 accumulate. Optional ReLU; fp32 and/or bf16 out.
// ---------------------------------------------------------------------------
__global__ __launch_bounds__(256) void gemm_bias(const ushort* __restrict__ A,
                                                 const ushort* __restrict__ BT,
                                                 const float* __restrict__ bias,
                                                 float* __restrict__ Cf,
                                                 ushort* __restrict__ Cb,
                                                 int M, int N, int K, int relu) {
    __shared__ ushort As[64][40];   // pad 40: 80B rows, 16B aligned
    __shared__ ushort Bs[64][40];
    int bid = blockIdx.x;
    int nbn = N >> 6;
    int bm = (bid / nbn) << 6;
    int bn = (bid % nbn) << 6;
    int tid = threadIdx.x;
    int w = tid >> 6, lane = tid & 63;
    int lr = lane & 15, lg = lane >> 4;

    floatx4 acc[4] = {};

    int sr = tid >> 2, sc = (tid & 3) << 3;
    const short8* ga = (const short8*)(A + (size_t)(bm + sr) * K + sc);
    const short8* gb = (const short8*)(BT + (size_t)(bn + sr) * K + sc);

    for (int kt = 0; kt < K; kt += 32) {
        *(short8*)&As[sr][sc] = *ga; ga += 4;   // advance 32 elems along K
        *(short8*)&Bs[sr][sc] = *gb; gb += 4;
        __syncthreads();
        short8 af  = *(const short8*)&As[w * 16 + lr][lg * 8];
        short8 b0  = *(const short8*)&Bs[lr][lg * 8];
        short8 b1  = *(const short8*)&Bs[16 + lr][lg * 8];
        short8 b2  = *(const short8*)&Bs[32 + lr][lg * 8];
        short8 b3  = *(const short8*)&Bs[48 + lr][lg * 8];
        mfma16x16x32(acc[0], af, b0);
        mfma16x16x32(acc[1], af, b1);
        mfma16x16x32(acc[2], af, b2);
        mfma16x16x32(acc[3], af, b3);
        __syncthreads();
    }

#pragma unroll
    for (int c = 0; c < 4; ++c) {
        int col = bn + c * 16 + lr;
        float bv = bias[col];
#pragma unroll
        for (int rr = 0; rr < 4; ++rr) {
            int rowi = bm + w * 16 + lg * 4 + rr;   // C/D: col=lane&15, row=(lane>>4)*4+reg
            float v = acc[c][rr] + bv;
            if (relu) v = fmaxf(v, 0.f);
            size_t idx = (size_t)rowi * N + col;
            if (Cf) Cf[idx] = v;
            if (Cb) Cb[idx] = f2bf(v);
        }
    }
}

// ---------------------------------------------------------------------------
// Flash-style attention. Block = (b, h, 16 q-rows); K/V chunks of 128 in LDS;
// online softmax in fp32. Thread map phase A: (q=tid&15, k=tid>>4 + 16*it);
// phase B: (r=tid>>4, c=tid&15, dims d0=4c..4c+3).
// ---------------------------------------------------------------------------
__global__ __launch_bounds__(256) void attention(const ushort* __restrict__ Q,
                                                 const ushort* __restrict__ K,
                                                 const ushort* __restrict__ V,
                                                 ushort* __restrict__ CTX) {
    __shared__ float  Qs[16][68];
    __shared__ ushort Ks[128][72];
    __shared__ ushort Vs[128][72];
    __shared__ float  Ps[16][132];

    int bid = blockIdx.x;
    int qt = bid & 127;            // S/16
    int hh = (bid >> 7) & 7;
    int bb = bid >> 10;
    int q0 = qt * 16;
    int tid = threadIdx.x;

    size_t base = ((size_t)bb * SS) * DD + hh * DHH;

    for (int idx = tid; idx < 16 * DHH; idx += 256) {
        int r = idx >> 6, d = idx & 63;
        Qs[r][d] = bf2f(Q[base + (size_t)(q0 + r) * DD + d]) * 0.125f; // /sqrt(64)
    }

    int r = tid >> 4, c = tid & 15, d0 = c * 4;
    float m = -1e30f, l = 0.f;
    float o0 = 0.f, o1 = 0.f, o2 = 0.f, o3 = 0.f;

    for (int ch = 0; ch < SS; ch += 128) {
        __syncthreads();   // protect Ks/Vs from prior-iter readers; covers Q load on iter 0
        {
            int kk = tid >> 1, co = (tid & 1) * 32;
            const short8* gk = (const short8*)(K + base + (size_t)(ch + kk) * DD + co);
            const short8* gv = (const short8*)(V + base + (size_t)(ch + kk) * DD + co);
            short8* lk = (short8*)&Ks[kk][co];
            short8* lv = (short8*)&Vs[kk][co];
            lk[0] = gk[0]; lk[1] = gk[1]; lk[2] = gk[2]; lk[3] = gk[3];
            lv[0] = gv[0]; lv[1] = gv[1]; lv[2] = gv[2]; lv[3] = gv[3];
        }
        __syncthreads();
        // scores: 16x128 into Ps
        {
            int q = tid & 15, kb = tid >> 4;
#pragma unroll
            for (int it = 0; it < 8; ++it) {
                int kk = kb + it * 16;
                const short8* krow = (const short8*)&Ks[kk][0];
                float s = 0.f;
#pragma unroll
                for (int j8 = 0; j8 < 8; ++j8) {
                    short8 kv = krow[j8];
                    const float* qp = &Qs[q][j8 * 8];
#pragma unroll
                    for (int e = 0; e < 8; ++e)
                        s += qp[e] * bf2f((unsigned short)kv[e]);
                }
                Ps[q][kk] = s;
            }
        }
        __syncthreads();
        // online softmax update (row r owned by 16 contiguous lanes of one wave)
        float pm = -1e30f;
#pragma unroll
        for (int j = 0; j < 8; ++j) pm = fmaxf(pm, Ps[r][c + j * 16]);
#pragma unroll
        for (int off = 8; off; off >>= 1) pm = fmaxf(pm, __shfl_xor(pm, off));
        float newm = fmaxf(m, pm);
        float scale = __expf(m - newm);
        float ps = 0.f;
#pragma unroll
        for (int j = 0; j < 8; ++j) {
            float e = __expf(Ps[r][c + j * 16] - newm);
            Ps[r][c + j * 16] = e;      // write-back by owner; same wave reads below
            ps += e;
        }
#pragma unroll
        for (int off = 8; off; off >>= 1) ps += __shfl_xor(ps, off);
        m = newm; l = l * scale + ps;
        o0 *= scale; o1 *= scale; o2 *= scale; o3 *= scale;
        // PV accumulate (Ps row written by this wave; Vs guarded by barriers)
#pragma unroll 4
        for (int kk = 0; kk < 128; ++kk) {
            float p = Ps[r][kk];
            short4_t vv = *(const short4_t*)&Vs[kk][d0];
            o0 += p * bf2f((unsigned short)vv[0]);
            o1 += p * bf2f((unsigned short)vv[1]);
            o2 += p * bf2f((unsigned short)vv[2]);
            o3 += p * bf2f((unsigned short)vv[3]);
        }
    }
    float rl = 1.f / l;
    size_t op = base + (size_t)(q0 + r) * DD + d0;
    CTX[op + 0] = f2bf(o0 * rl);
    CTX[op + 1] = f2bf(o1 * rl);
    CTX[op + 2] = f2bf(o2 * rl);
    CTX[op + 3] = f2bf(o3 * rl);
}

// ---------------------------------------------------------------------------
// hout = LayerNorm(hin + yin) * g + b  (fp32), plus bf16 copy to bout.
// One block per row of 512.
// ---------------------------------------------------------------------------
__global__ __launch_bounds__(256) void add_ln(const float* __restrict__ hin,
                                              const float* __restrict__ yin,
                                              const float* __restrict__ g,
                                              const float* __restrict__ b,
                                              float* __restrict__ hout,
                                              ushort* __restrict__ bout) {
    __shared__ float red[4];
    __shared__ float red2[4];
    int row = blockIdx.x, tid = threadIdx.x;
    const float* hr = hin + (size_t)row * DD;
    const float* yr = yin + (size_t)row * DD;
    float v0 = hr[tid] + yr[tid];
    float v1 = hr[tid + 256] + yr[tid + 256];
    float s = v0 + v1;
#pragma unroll
    for (int off = 32; off; off >>= 1) s += __shfl_xor(s, off);
    if ((tid & 63) == 0) red[tid >> 6] = s;
    __syncthreads();
    float mean = (red[0] + red[1] + red[2] + red[3]) * (1.f / 512.f);
    float d0 = v0 - mean, d1 = v1 - mean;
    float s2 = d0 * d0 + d1 * d1;
#pragma unroll
    for (int off = 32; off; off >>= 1) s2 += __shfl_xor(s2, off);
    if ((tid & 63) == 0) red2[tid >> 6] = s2;
    __syncthreads();
    float var = (red2[0] + red2[1] + red2[2] + red2[3]) * (1.f / 512.f);
    float rstd = rsqrtf(var + 1e-5f);
    float r0 = d0 * rstd * g[tid] + b[tid];
    float r1 = d1 * rstd * g[tid + 256] + b[tid + 256];
    float* ho = hout + (size_t)row * DD;
    ho[tid] = r0; ho[tid + 256] = r1;
    bout[(size_t)row * DD + tid] = f2bf(r0);
    bout[(size_t)row * DD + tid + 256] = f2bf(r1);
}

// ---------------------------------------------------------------------------
extern "C" void kernel_launch(void* const* d_in, const int* in_sizes, int n_in,
                              void* d_out, int out_size, void* d_ws, size_t ws_size,
                              hipStream_t stream) {
    const int*   x    = (const int*)d_in[0];
    const float* emb  = (const float*)d_in[1];
    const float* Wq   = (const float*)d_in[2];
    const float* bq   = (const float*)d_in[3];
    const float* Wk   = (const float*)d_in[4];
    const float* bk   = (const float*)d_in[5];
    const float* Wv   = (const float*)d_in[6];
    const float* bv   = (const float*)d_in[7];
    const float* Wo   = (const float*)d_in[8];
    const float* bo   = (const float*)d_in[9];
    const float* W1   = (const float*)d_in[10];
    const float* b1   = (const float*)d_in[11];
    const float* W2   = (const float*)d_in[12];
    const float* b2   = (const float*)d_in[13];
    const float* g1   = (const float*)d_in[14];
    const float* be1  = (const float*)d_in[15];
    const float* g2   = (const float*)d_in[16];
    const float* be2  = (const float*)d_in[17];
    float* out = (float*)d_out;

    char* ws = (char*)d_ws;
    size_t off = 0;
    auto alloc = [&](size_t bytes) -> void* {
        void* p = ws + off;
        off += (bytes + 255) & ~(size_t)255;
        return p;
    };
    float*  h    = (float*)alloc((size_t)NROWS * DD * 4);
    float*  y    = (float*)alloc((size_t)NROWS * DD * 4);
    ushort* hb   = (ushort*)alloc((size_t)NROWS * DD * 2);
    ushort* qb   = (ushort*)alloc((size_t)NROWS * DD * 2);
    ushort* kb   = (ushort*)alloc((size_t)NROWS * DD * 2);
    ushort* vb   = (ushort*)alloc((size_t)NROWS * DD * 2);
    ushort* ctxb = (ushort*)alloc((size_t)NROWS * DD * 2);
    ushort* ff1  = qb;  // FF1 activations [4096,2048] alias dead qb..ctxb (16MB)
    ushort* WqT  = (ushort*)alloc((size_t)6 * DD * DD * 2);
    ushort* WkT  = (ushort*)alloc((size_t)6 * DD * DD * 2);
    ushort* WvT  = (ushort*)alloc((size_t)6 * DD * DD * 2);
    ushort* WoT  = (ushort*)alloc((size_t)6 * DD * DD * 2);
    ushort* W1T  = (ushort*)alloc((size_t)6 * DD * 2048 * 2);
    ushort* W2T  = (ushort*)alloc((size_t)6 * DD * 2048 * 2);

    // Diagnostic guard: if ws is too small, leave d_out zeroed (absmax ~3.9
    // signature) instead of corrupting memory with OOB writes.
    if (ws_size < off) return;

    dim3 tb(32, 8);
    transpose_k<<<dim3(16, 16, 6), tb, 0, stream>>>(Wq, WqT, 512, 512);
    transpose_k<<<dim3(16, 16, 6), tb, 0, stream>>>(Wk, WkT, 512, 512);
    transpose_k<<<dim3(16, 16, 6), tb, 0, stream>>>(Wv, WvT, 512, 512);
    transpose_k<<<dim3(16, 16, 6), tb, 0, stream>>>(Wo, WoT, 512, 512);
    transpose_k<<<dim3(64, 16, 6), tb, 0, stream>>>(W1, W1T, 512, 2048);   // ->[2048,512]
    transpose_k<<<dim3(16, 64, 6), tb, 0, stream>>>(W2, W2T, 2048, 512);   // ->[512,2048]

    embed_pe<<<NROWS, 256, 0, stream>>>(x, emb, h, hb);

    for (int l = 0; l < 6; ++l) {
        const int sqo = l * 512 * 512;     // square weight offset
        const int fto = l * 512 * 2048;    // ff weight offset
        gemm_bias<<<512, 256, 0, stream>>>(hb, WqT + sqo, bq + l * 512, nullptr, qb, NROWS, 512, 512, 0);
        gemm_bias<<<512, 256, 0, stream>>>(hb, WkT + sqo, bk + l * 512, nullptr, kb, NROWS, 512, 512, 0);
        gemm_bias<<<512, 256, 0, stream>>>(hb, WvT + sqo, bv + l * 512, nullptr, vb, NROWS, 512, 512, 0);
        attention<<<2048, 256, 0, stream>>>(qb, kb, vb, ctxb);
        gemm_bias<<<512, 256, 0, stream>>>(ctxb, WoT + sqo, bo + l * 512, y, nullptr, NROWS, 512, 512, 0);
        add_ln<<<NROWS, 256, 0, stream>>>(h, y, g1 + l * 512, be1 + l * 512, h, hb);
        gemm_bias<<<2048, 256, 0, stream>>>(hb, W1T + fto, b1 + l * 2048, nullptr, ff1, NROWS, 2048, 512, 1);
        gemm_bias<<<512, 256, 0, stream>>>(ff1, W2T + fto, b2 + l * 512, y, nullptr, NROWS, 512, 2048, 0);
        add_ln<<<NROWS, 256, 0, stream>>>(h, y, g2 + l * 512, be2 + l * 512,
                                          (l == 5) ? out : h, hb);
    }
}

// Round 4
// 1318.472 us; speedup vs baseline: 5.0082x; 5.0082x over previous
//
#include <hip/hip_runtime.h>
#include <hip/hip_bf16.h>

// ---------------------------------------------------------------------------
// TransformerEncoder: B=2, S=2048, D=512, H=8, DH=64, DF=2048, NX=6 layers
// I/O dtype: FP32. Internals: bf16 MFMA GEMMs + MFMA flash attention,
// fp32 residual stream + LayerNorm.
// ---------------------------------------------------------------------------

typedef __attribute__((ext_vector_type(4))) float  floatx4;
typedef __attribute__((ext_vector_type(8))) short  short8;
typedef __bf16 bf16x8 __attribute__((ext_vector_type(8)));

#define SS 2048
#define DD 512
#define HH 8
#define DHH 64
#define NROWS 4096   /* B*S */

__device__ __forceinline__ float bf2f(unsigned short u) {
    union { float f; unsigned int i; } x; x.i = ((unsigned int)u) << 16; return x.f;
}
__device__ __forceinline__ unsigned short f2bf(float f) {
    union { float f; unsigned int i; } x; x.f = f;
    unsigned int lsb = (x.i >> 16) & 1u;
    x.i += 0x7fffu + lsb;               // round-to-nearest-even
    return (unsigned short)(x.i >> 16);
}

#if __has_builtin(__builtin_amdgcn_mfma_f32_16x16x32_bf16)
__device__ __forceinline__ void mfma16x16x32(floatx4& d, short8 a, short8 b) {
    bf16x8 ab, bb;
    __builtin_memcpy(&ab, &a, 16);
    __builtin_memcpy(&bb, &b, 16);
    d = __builtin_amdgcn_mfma_f32_16x16x32_bf16(ab, bb, d, 0, 0, 0);
}
#else
__device__ __forceinline__ void mfma16x16x32(floatx4& d, short8 a, short8 b) {
    asm volatile("s_nop 1\n\t"
                 "v_mfma_f32_16x16x32_bf16 %0, %1, %2, %0\n\t"
                 "s_nop 7\n\t"
                 "s_nop 7"
                 : "+v"(d) : "v"(a), "v"(b));
}
#endif

// ---------------------------------------------------------------------------
// Weight transpose + fp32->bf16: W [z][R][C] fp32 -> WT [z][C][R] bf16
// ---------------------------------------------------------------------------
__global__ __launch_bounds__(256) void transpose_k(const float* __restrict__ W,
                                                   ushort* __restrict__ WT,
                                                   int R, int C) {
    __shared__ ushort t[32][33];
    int z = blockIdx.z;
    const float* Wz = W + (size_t)z * R * C;
    ushort* WTz = WT + (size_t)z * R * C;
    int c0 = blockIdx.x * 32, r0 = blockIdx.y * 32;
    int x = threadIdx.x, y = threadIdx.y;         // (32,8)
#pragma unroll
    for (int i = 0; i < 32; i += 8)
        t[y + i][x] = f2bf(Wz[(size_t)(r0 + y + i) * C + c0 + x]);
    __syncthreads();
#pragma unroll
    for (int i = 0; i < 32; i += 8)
        WTz[(size_t)(c0 + y + i) * R + r0 + x] = t[x][y + i];
}

// ---------------------------------------------------------------------------
// Embedding + positional encoding.
// ---------------------------------------------------------------------------
__global__ __launch_bounds__(256) void embed_pe(const int* __restrict__ x,
                                                const float* __restrict__ emb,
                                                float* __restrict__ h,
                                                ushort* __restrict__ hb) {
    __shared__ int isI32;
    int row = blockIdx.x, tid = threadIdx.x;
    if (tid == 0) isI32 = 0;
    __syncthreads();
    int acc = 0;
    for (int i = tid; i < 2048; i += 256) acc |= x[2 * i + 1];
    if (acc) isI32 = 1;
    __syncthreads();
    int tok = isI32 ? x[row] : x[2 * row];
    int s = row & (SS - 1);
    const float* er = emb + (size_t)tok * DD;
    for (int c = tid; c < DD; c += 256) {
        float e = er[c] * 22.62741699796952f;              // sqrt(512)
        float freq = __expf(-((float)c * (1.f / 256.f)) * 9.210340371976184f); // ln(1e4)
        float ang = (float)s * freq;
        float pe = (c & 1) ? cosf(ang) : sinf(ang);
        float val = e + pe;
        h[(size_t)row * DD + c] = val;
        hb[(size_t)row * DD + c] = f2bf(val);
    }
}

// ---------------------------------------------------------------------------
// GEMM: C[M,N] = A[M,K] @ B[K,N] + bias, B supplied TRANSPOSED (BT[N,K], bf16).
// 64x64 tile, BK=32, 4 waves. MFMA 16x16x32; fp32 acc. Optional ReLU.
// ---------------------------------------------------------------------------
__global__ __launch_bounds__(256) void gemm_bias(const ushort* __restrict__ A,
                                                 const ushort* __restrict__ BT,
                                                 const float* __restrict__ bias,
                                                 float* __restrict__ Cf,
                                                 ushort* __restrict__ Cb,
                                                 int M, int N, int K, int relu) {
    __shared__ ushort As[64][40];
    __shared__ ushort Bs[64][40];
    int bid = blockIdx.x;
    int nbn = N >> 6;
    int bm = (bid / nbn) << 6;
    int bn = (bid % nbn) << 6;
    int tid = threadIdx.x;
    int w = tid >> 6, lane = tid & 63;
    int lr = lane & 15, lg = lane >> 4;

    floatx4 acc[4] = {};

    int sr = tid >> 2, sc = (tid & 3) << 3;
    const short8* ga = (const short8*)(A + (size_t)(bm + sr) * K + sc);
    const short8* gb = (const short8*)(BT + (size_t)(bn + sr) * K + sc);

    for (int kt = 0; kt < K; kt += 32) {
        *(short8*)&As[sr][sc] = *ga; ga += 4;
        *(short8*)&Bs[sr][sc] = *gb; gb += 4;
        __syncthreads();
        short8 af  = *(const short8*)&As[w * 16 + lr][lg * 8];
        short8 b0  = *(const short8*)&Bs[lr][lg * 8];
        short8 b1  = *(const short8*)&Bs[16 + lr][lg * 8];
        short8 b2  = *(const short8*)&Bs[32 + lr][lg * 8];
        short8 b3  = *(const short8*)&Bs[48 + lr][lg * 8];
        mfma16x16x32(acc[0], af, b0);
        mfma16x16x32(acc[1], af, b1);
        mfma16x16x32(acc[2], af, b2);
        mfma16x16x32(acc[3], af, b3);
        __syncthreads();
    }

#pragma unroll
    for (int c = 0; c < 4; ++c) {
        int col = bn + c * 16 + lr;
        float bv = bias[col];
#pragma unroll
        for (int rr = 0; rr < 4; ++rr) {
            int rowi = bm + w * 16 + lg * 4 + rr;
            float v = acc[c][rr] + bv;
            if (relu) v = fmaxf(v, 0.f);
            size_t idx = (size_t)rowi * N + col;
            if (Cf) Cf[idx] = v;
            if (Cb) Cb[idx] = f2bf(v);
        }
    }
}

// ---------------------------------------------------------------------------
// MFMA flash attention. Block = 128 threads = 2 waves; each wave 16 q-rows
// (QBLK=32). KV chunks of 64 staged in LDS (K row-major, V transposed).
// Fragment conventions identical to gemm_bias (validated r3):
//   A: row=lane&15, k at (lane>>4)*8;  B: col=lane&15, same k;
//   C/D: col=lane&15, row=(lane>>4)*4+reg.
// Softmax in-register on C/D layout; P via per-wave LDS round-trip.
// All LDS rows padded to 72 ushorts (144B = 9 bank-groups, coprime with 8).
// ---------------------------------------------------------------------------
__global__ __launch_bounds__(128) void attn_mfma(const ushort* __restrict__ Q,
                                                 const ushort* __restrict__ K,
                                                 const ushort* __restrict__ V,
                                                 ushort* __restrict__ CTX) {
    __shared__ ushort Ks[64][72];     // [key][dim]
    __shared__ ushort VsT[64][72];    // [dim][key]
    __shared__ ushort Ps[2][16][72];  // per-wave P round-trip [q][key]

    int bid = blockIdx.x;
    int qt = bid & 63;             // 64 q-tiles of 32 rows
    int hh = (bid >> 6) & 7;
    int bb = bid >> 9;
    int q0 = qt * 32;
    int tid = threadIdx.x;
    int w = tid >> 6, l = tid & 63;
    int c = l & 15, g = l >> 4;

    size_t base = (size_t)bb * SS * DD + hh * DHH;

    // Q fragments (wave's 16 rows, 64 dims = 2 k-steps)
    short8 qf[2];
    {
        const ushort* qp = Q + base + (size_t)(q0 + w * 16 + c) * DD + g * 8;
        qf[0] = *(const short8*)qp;
        qf[1] = *(const short8*)(qp + 32);
    }

    floatx4 O[4] = {};                        // O[dtile][reg]: col=d, row=q
    float mx[4] = {-1e30f, -1e30f, -1e30f, -1e30f};
    float dn[4] = {};

    for (int ch = 0; ch < SS; ch += 64) {
        __syncthreads();   // previous chunk's readers done with Ks/VsT
        // ---- stage K rows (thread: key=tid>>1, dims (tid&1)*32..+31) ----
        {
            int kk = tid >> 1, d0 = (tid & 1) * 32;
            const short8* gk = (const short8*)(K + base + (size_t)(ch + kk) * DD + d0);
            *(short8*)&Ks[kk][d0]      = gk[0];
            *(short8*)&Ks[kk][d0 + 8]  = gk[1];
            *(short8*)&Ks[kk][d0 + 16] = gk[2];
            *(short8*)&Ks[kk][d0 + 24] = gk[3];
        }
        // ---- stage V transposed, pair-packed u32 (conflict-free) ----
        {
            int kp = (tid & 31) * 2;          // even key
            int dv = (tid >> 5) * 16;         // 16 dims
            const ushort* gv0 = V + base + (size_t)(ch + kp) * DD + dv;
            const ushort* gv1 = gv0 + DD;
            short8 va0 = *(const short8*)gv0;
            short8 va1 = *(const short8*)(gv0 + 8);
            short8 vb0 = *(const short8*)gv1;
            short8 vb1 = *(const short8*)(gv1 + 8);
#pragma unroll
            for (int j = 0; j < 8; ++j) {
                unsigned int lo = (unsigned short)va0[j], hi = (unsigned short)vb0[j];
                *(unsigned int*)&VsT[dv + j][kp] = lo | (hi << 16);
            }
#pragma unroll
            for (int j = 0; j < 8; ++j) {
                unsigned int lo = (unsigned short)va1[j], hi = (unsigned short)vb1[j];
                *(unsigned int*)&VsT[dv + 8 + j][kp] = lo | (hi << 16);
            }
        }
        __syncthreads();

        // ---- QK^T: S[t] = Q(16q x 64d) . K^T -> 16q x 16k per tile ----
        floatx4 S[4] = {};
#pragma unroll
        for (int t = 0; t < 4; ++t) {
            short8 k0 = *(const short8*)&Ks[t * 16 + c][g * 8];
            short8 k1 = *(const short8*)&Ks[t * 16 + c][32 + g * 8];
            mfma16x16x32(S[t], qf[0], k0);
            mfma16x16x32(S[t], qf[1], k1);
        }

        // ---- online softmax (scores scaled by 1/8 inside exp) ----
#pragma unroll
        for (int r = 0; r < 4; ++r) {
            float pm = fmaxf(fmaxf(S[0][r], S[1][r]), fmaxf(S[2][r], S[3][r]));
            pm = fmaxf(pm, __shfl_xor(pm, 1));
            pm = fmaxf(pm, __shfl_xor(pm, 2));
            pm = fmaxf(pm, __shfl_xor(pm, 4));
            pm = fmaxf(pm, __shfl_xor(pm, 8));
            float nmr = fmaxf(mx[r], pm);
            float scr = __expf((mx[r] - nmr) * 0.125f);
            float mb = -nmr * 0.125f;
            float e0 = __expf(fmaf(S[0][r], 0.125f, mb));
            float e1 = __expf(fmaf(S[1][r], 0.125f, mb));
            float e2 = __expf(fmaf(S[2][r], 0.125f, mb));
            float e3 = __expf(fmaf(S[3][r], 0.125f, mb));
            float ps = e0 + e1 + e2 + e3;
            ps += __shfl_xor(ps, 1);
            ps += __shfl_xor(ps, 2);
            ps += __shfl_xor(ps, 4);
            ps += __shfl_xor(ps, 8);
            dn[r] = dn[r] * scr + ps;
            mx[r] = nmr;
            O[0][r] *= scr; O[1][r] *= scr; O[2][r] *= scr; O[3][r] *= scr;
            // store P row q=4g+r (bank-checked: 2-way max)
            int q = 4 * g + r;
            Ps[w][q][c]      = f2bf(e0);
            Ps[w][q][16 + c] = f2bf(e1);
            Ps[w][q][32 + c] = f2bf(e2);
            Ps[w][q][48 + c] = f2bf(e3);
        }

        // ---- PV: O += P(16q x 64k) . V(64k x 64d) ----
        // (compiler orders Ps read-after-write via lgkmcnt; same-wave only)
#pragma unroll
        for (int s = 0; s < 2; ++s) {
            short8 pa = *(const short8*)&Ps[w][c][s * 32 + g * 8];
#pragma unroll
            for (int dt = 0; dt < 4; ++dt) {
                short8 vb = *(const short8*)&VsT[dt * 16 + c][s * 32 + g * 8];
                mfma16x16x32(O[dt], pa, vb);
            }
        }
    }

    // ---- epilogue: O/l -> CTX (bf16) ----
    float inv[4];
#pragma unroll
    for (int r = 0; r < 4; ++r) inv[r] = 1.f / dn[r];
#pragma unroll
    for (int dt = 0; dt < 4; ++dt) {
#pragma unroll
        for (int r = 0; r < 4; ++r) {
            size_t op = base + (size_t)(q0 + w * 16 + 4 * g + r) * DD + dt * 16 + c;
            CTX[op] = f2bf(O[dt][r] * inv[r]);
        }
    }
}

// ---------------------------------------------------------------------------
// hout = LayerNorm(hin + yin) * g + b (fp32), plus bf16 copy to bout.
// ---------------------------------------------------------------------------
__global__ __launch_bounds__(256) void add_ln(const float* __restrict__ hin,
                                              const float* __restrict__ yin,
                                              const float* __restrict__ g,
                                              const float* __restrict__ b,
                                              float* __restrict__ hout,
                                              ushort* __restrict__ bout) {
    __shared__ float red[4];
    __shared__ float red2[4];
    int row = blockIdx.x, tid = threadIdx.x;
    const float* hr = hin + (size_t)row * DD;
    const float* yr = yin + (size_t)row * DD;
    float v0 = hr[tid] + yr[tid];
    float v1 = hr[tid + 256] + yr[tid + 256];
    float s = v0 + v1;
#pragma unroll
    for (int off = 32; off; off >>= 1) s += __shfl_xor(s, off);
    if ((tid & 63) == 0) red[tid >> 6] = s;
    __syncthreads();
    float mean = (red[0] + red[1] + red[2] + red[3]) * (1.f / 512.f);
    float d0 = v0 - mean, d1 = v1 - mean;
    float s2 = d0 * d0 + d1 * d1;
#pragma unroll
    for (int off = 32; off; off >>= 1) s2 += __shfl_xor(s2, off);
    if ((tid & 63) == 0) red2[tid >> 6] = s2;
    __syncthreads();
    float var = (red2[0] + red2[1] + red2[2] + red2[3]) * (1.f / 512.f);
    float rstd = rsqrtf(var + 1e-5f);
    float r0 = d0 * rstd * g[tid] + b[tid];
    float r1 = d1 * rstd * g[tid + 256] + b[tid + 256];
    float* ho = hout + (size_t)row * DD;
    ho[tid] = r0; ho[tid + 256] = r1;
    bout[(size_t)row * DD + tid] = f2bf(r0);
    bout[(size_t)row * DD + tid + 256] = f2bf(r1);
}

// ---------------------------------------------------------------------------
extern "C" void kernel_launch(void* const* d_in, const int* in_sizes, int n_in,
                              void* d_out, int out_size, void* d_ws, size_t ws_size,
                              hipStream_t stream) {
    const int*   x    = (const int*)d_in[0];
    const float* emb  = (const float*)d_in[1];
    const float* Wq   = (const float*)d_in[2];
    const float* bq   = (const float*)d_in[3];
    const float* Wk   = (const float*)d_in[4];
    const float* bk   = (const float*)d_in[5];
    const float* Wv   = (const float*)d_in[6];
    const float* bv   = (const float*)d_in[7];
    const float* Wo   = (const float*)d_in[8];
    const float* bo   = (const float*)d_in[9];
    const float* W1   = (const float*)d_in[10];
    const float* b1   = (const float*)d_in[11];
    const float* W2   = (const float*)d_in[12];
    const float* b2   = (const float*)d_in[13];
    const float* g1   = (const float*)d_in[14];
    const float* be1  = (const float*)d_in[15];
    const float* g2   = (const float*)d_in[16];
    const float* be2  = (const float*)d_in[17];
    float* out = (float*)d_out;

    char* ws = (char*)d_ws;
    size_t off = 0;
    auto alloc = [&](size_t bytes) -> void* {
        void* p = ws + off;
        off += (bytes + 255) & ~(size_t)255;
        return p;
    };
    float*  h    = (float*)alloc((size_t)NROWS * DD * 4);
    float*  y    = (float*)alloc((size_t)NROWS * DD * 4);
    ushort* hb   = (ushort*)alloc((size_t)NROWS * DD * 2);
    ushort* qb   = (ushort*)alloc((size_t)NROWS * DD * 2);
    ushort* kb   = (ushort*)alloc((size_t)NROWS * DD * 2);
    ushort* vb   = (ushort*)alloc((size_t)NROWS * DD * 2);
    ushort* ctxb = (ushort*)alloc((size_t)NROWS * DD * 2);
    ushort* ff1  = qb;  // FF1 activations alias dead qb..ctxb (16MB)
    ushort* WqT  = (ushort*)alloc((size_t)6 * DD * DD * 2);
    ushort* WkT  = (ushort*)alloc((size_t)6 * DD * DD * 2);
    ushort* WvT  = (ushort*)alloc((size_t)6 * DD * DD * 2);
    ushort* WoT  = (ushort*)alloc((size_t)6 * DD * DD * 2);
    ushort* W1T  = (ushort*)alloc((size_t)6 * DD * 2048 * 2);
    ushort* W2T  = (ushort*)alloc((size_t)6 * DD * 2048 * 2);

    if (ws_size < off) return;   // diagnostic guard (zeros signature)

    dim3 tb(32, 8);
    transpose_k<<<dim3(16, 16, 6), tb, 0, stream>>>(Wq, WqT, 512, 512);
    transpose_k<<<dim3(16, 16, 6), tb, 0, stream>>>(Wk, WkT, 512, 512);
    transpose_k<<<dim3(16, 16, 6), tb, 0, stream>>>(Wv, WvT, 512, 512);
    transpose_k<<<dim3(16, 16, 6), tb, 0, stream>>>(Wo, WoT, 512, 512);
    transpose_k<<<dim3(64, 16, 6), tb, 0, stream>>>(W1, W1T, 512, 2048);
    transpose_k<<<dim3(16, 64, 6), tb, 0, stream>>>(W2, W2T, 2048, 512);

    embed_pe<<<NROWS, 256, 0, stream>>>(x, emb, h, hb);

    for (int l = 0; l < 6; ++l) {
        const int sqo = l * 512 * 512;
        const int fto = l * 512 * 2048;
        gemm_bias<<<512, 256, 0, stream>>>(hb, WqT + sqo, bq + l * 512, nullptr, qb, NROWS, 512, 512, 0);
        gemm_bias<<<512, 256, 0, stream>>>(hb, WkT + sqo, bk + l * 512, nullptr, kb, NROWS, 512, 512, 0);
        gemm_bias<<<512, 256, 0, stream>>>(hb, WvT + sqo, bv + l * 512, nullptr, vb, NROWS, 512, 512, 0);
        attn_mfma<<<1024, 128, 0, stream>>>(qb, kb, vb, ctxb);
        gemm_bias<<<512, 256, 0, stream>>>(ctxb, WoT + sqo, bo + l * 512, y, nullptr, NROWS, 512, 512, 0);
        add_ln<<<NROWS, 256, 0, stream>>>(h, y, g1 + l * 512, be1 + l * 512, h, hb);
        gemm_bias<<<2048, 256, 0, stream>>>(hb, W1T + fto, b1 + l * 2048, nullptr, ff1, NROWS, 2048, 512, 1);
        gemm_bias<<<512, 256, 0, stream>>>(ff1, W2T + fto, b2 + l * 512, y, nullptr, NROWS, 512, 2048, 0);
        add_ln<<<NROWS, 256, 0, stream>>>(h, y, g2 + l * 512, be2 + l * 512,
                                          (l == 5) ? out : h, hb);
    }
}

// Round 5
// 1110.824 us; speedup vs baseline: 5.9444x; 1.1869x over previous
//
#include <hip/hip_runtime.h>
#include <hip/hip_bf16.h>

// ---------------------------------------------------------------------------
// TransformerEncoder: B=2, S=2048, D=512, H=8, DH=64, DF=2048, NX=6 layers
// I/O fp32. bf16 MFMA GEMMs (m97-style 128-tile + global_load_lds),
// fused QKV projection, 4-wave MFMA flash attention, fp32 residual + LN.
// ---------------------------------------------------------------------------

typedef __attribute__((ext_vector_type(4))) float  floatx4;
typedef __attribute__((ext_vector_type(8))) short  short8;
typedef __bf16 bf16x8 __attribute__((ext_vector_type(8)));

#define SS 2048
#define DD 512
#define HH 8
#define DHH 64
#define NROWS 4096   /* B*S */
#define QS 1536      /* fused qkv row stride */

__device__ __forceinline__ float bf2f(unsigned short u) {
    union { float f; unsigned int i; } x; x.i = ((unsigned int)u) << 16; return x.f;
}
__device__ __forceinline__ unsigned short f2bf(float f) {
    union { float f; unsigned int i; } x; x.f = f;
    unsigned int lsb = (x.i >> 16) & 1u;
    x.i += 0x7fffu + lsb;
    return (unsigned short)(x.i >> 16);
}

#if __has_builtin(__builtin_amdgcn_mfma_f32_16x16x32_bf16)
__device__ __forceinline__ void mfma16x16x32(floatx4& d, short8 a, short8 b) {
    bf16x8 ab, bb;
    __builtin_memcpy(&ab, &a, 16);
    __builtin_memcpy(&bb, &b, 16);
    d = __builtin_amdgcn_mfma_f32_16x16x32_bf16(ab, bb, d, 0, 0, 0);
}
#else
__device__ __forceinline__ void mfma16x16x32(floatx4& d, short8 a, short8 b) {
    asm volatile("s_nop 1\n\t"
                 "v_mfma_f32_16x16x32_bf16 %0, %1, %2, %0\n\t"
                 "s_nop 7\n\t"
                 "s_nop 7"
                 : "+v"(d) : "v"(a), "v"(b));
}
#endif

// stage 16B/lane: g = per-lane global src, lbase = wave-uniform LDS chunk base,
// HW writes lbase + lane*16 (guide §5: dest is uniform-base + lane*size).
#if __has_builtin(__builtin_amdgcn_global_load_lds)
#define HAS_GLOAD 1
__device__ __forceinline__ void stage16(const ushort* g, ushort* lbase, int lane) {
    __builtin_amdgcn_global_load_lds(
        (const __attribute__((address_space(1))) unsigned int*)g,
        (__attribute__((address_space(3))) unsigned int*)lbase, 16, 0, 0);
}
#else
#define HAS_GLOAD 0
__device__ __forceinline__ void stage16(const ushort* g, ushort* lbase, int lane) {
    *(short8*)(lbase + lane * 8) = *(const short8*)g;
}
#endif

// ---------------------------------------------------------------------------
// Weight transpose + fp32->bf16: W [z][R][C] fp32 -> dst [z*zstride + C*R] bf16
// ---------------------------------------------------------------------------
__global__ __launch_bounds__(256) void transpose_k(const float* __restrict__ W,
                                                   ushort* __restrict__ WT,
                                                   int R, int C, int zstride) {
    __shared__ ushort t[32][33];
    int z = blockIdx.z;
    const float* Wz = W + (size_t)z * R * C;
    ushort* WTz = WT + (size_t)z * zstride;
    int c0 = blockIdx.x * 32, r0 = blockIdx.y * 32;
    int x = threadIdx.x, y = threadIdx.y;         // (32,8)
#pragma unroll
    for (int i = 0; i < 32; i += 8)
        t[y + i][x] = f2bf(Wz[(size_t)(r0 + y + i) * C + c0 + x]);
    __syncthreads();
#pragma unroll
    for (int i = 0; i < 32; i += 8)
        WTz[(size_t)(c0 + y + i) * R + r0 + x] = t[x][y + i];
}

// concat per-layer q/k/v biases into [6][1536]
__global__ __launch_bounds__(512) void concat_bias(const float* __restrict__ bq,
                                                   const float* __restrict__ bk,
                                                   const float* __restrict__ bv,
                                                   float* __restrict__ qkvB) {
    int l = blockIdx.x, t = threadIdx.x;
    qkvB[l * QS + t]        = bq[l * DD + t];
    qkvB[l * QS + 512 + t]  = bk[l * DD + t];
    qkvB[l * QS + 1024 + t] = bv[l * DD + t];
}

// ---------------------------------------------------------------------------
// Embedding + positional encoding.
// ---------------------------------------------------------------------------
__global__ __launch_bounds__(256) void embed_pe(const int* __restrict__ x,
                                                const float* __restrict__ emb,
                                                float* __restrict__ h,
                                                ushort* __restrict__ hb) {
    __shared__ int isI32;
    int row = blockIdx.x, tid = threadIdx.x;
    if (tid == 0) isI32 = 0;
    __syncthreads();
    int acc = 0;
    for (int i = tid; i < 2048; i += 256) acc |= x[2 * i + 1];
    if (acc) isI32 = 1;
    __syncthreads();
    int tok = isI32 ? x[row] : x[2 * row];
    int s = row & (SS - 1);
    const float* er = emb + (size_t)tok * DD;
    for (int c = tid; c < DD; c += 256) {
        float e = er[c] * 22.62741699796952f;              // sqrt(512)
        float freq = __expf(-((float)c * (1.f / 256.f)) * 9.210340371976184f);
        float ang = (float)s * freq;
        float pe = (c & 1) ? cosf(ang) : sinf(ang);
        float val = e + pe;
        h[(size_t)row * DD + c] = val;
        hb[(size_t)row * DD + c] = f2bf(val);
    }
}

// ---------------------------------------------------------------------------
// m97-style GEMM: C[M,N] = A[M,K] @ BT[N,K]^T + bias. BM=128, BK=32,
// 256 threads = 4 waves. BN=128: waves 2x2, acc 4x4. BN=64: waves 4x1, acc 2x4.
// Linear LDS [.][32], staged via global_load_lds width 16 (1KB/wave-issue).
// ---------------------------------------------------------------------------
template <int BN>
__global__ __launch_bounds__(256) void gemm128(const ushort* __restrict__ A,
                                               const ushort* __restrict__ BT,
                                               const float* __restrict__ bias,
                                               float* __restrict__ Cf,
                                               ushort* __restrict__ Cb,
                                               int M, int N, int K, int relu) {
    constexpr int MI = (BN == 128) ? 4 : 2;   // 16-row tiles per wave
    constexpr int NI = 4;                     // 16-col tiles per wave
    __shared__ ushort As[128 * 32];
    __shared__ ushort Bs[BN * 32];

    int bid = blockIdx.x;
    int nbn = N / BN;
    int bm = (bid / nbn) * 128;
    int bn = (bid % nbn) * BN;
    int tid = threadIdx.x;
    int lane = tid & 63, w = tid >> 6;
    int lr = lane & 15, lg = lane >> 4;

    // staging addresses: chunk = 16 rows x 32 cols = 1KB
    int srow = lane >> 2, scol = (lane & 3) * 8;
    const ushort* gA0 = A + (size_t)(bm + w * 32 + srow) * K + scol;
    const ushort* gA1 = gA0 + (size_t)16 * K;
    ushort* lA0 = As + (w * 2 + 0) * 512;
    ushort* lA1 = As + (w * 2 + 1) * 512;
    const ushort* gB0;
    const ushort* gB1 = nullptr;
    ushort* lB0;
    ushort* lB1 = nullptr;
    if (BN == 128) {
        gB0 = BT + (size_t)(bn + w * 32 + srow) * K + scol;
        gB1 = gB0 + (size_t)16 * K;
        lB0 = Bs + (w * 2 + 0) * 512;
        lB1 = Bs + (w * 2 + 1) * 512;
    } else {
        gB0 = BT + (size_t)(bn + w * 16 + srow) * K + scol;
        lB0 = Bs + w * 512;
    }

    int wr = (BN == 128) ? (w >> 1) * 64 : w * 32;
    int wc = (BN == 128) ? (w & 1) * 64 : 0;

    floatx4 acc[MI][NI] = {};

    for (int kt = 0; kt < K; kt += 32) {
        stage16(gA0, lA0, lane);
        stage16(gA1, lA1, lane);
        stage16(gB0, lB0, lane);
        if (BN == 128) stage16(gB1, lB1, lane);
        __syncthreads();          // compiler drains vmcnt before barrier
        short8 af[MI], bf[NI];
#pragma unroll
        for (int mi = 0; mi < MI; ++mi)
            af[mi] = *(const short8*)&As[(wr + mi * 16 + lr) * 32 + lg * 8];
#pragma unroll
        for (int ni = 0; ni < NI; ++ni)
            bf[ni] = *(const short8*)&Bs[(wc + ni * 16 + lr) * 32 + lg * 8];
#pragma unroll
        for (int mi = 0; mi < MI; ++mi)
#pragma unroll
            for (int ni = 0; ni < NI; ++ni)
                mfma16x16x32(acc[mi][ni], af[mi], bf[ni]);
        __syncthreads();
        gA0 += 32; gA1 += 32; gB0 += 32;
        if (BN == 128) gB1 += 32;
    }

#pragma unroll
    for (int ni = 0; ni < NI; ++ni) {
        int col = bn + wc + ni * 16 + lr;
        float bv = bias[col];
#pragma unroll
        for (int mi = 0; mi < MI; ++mi) {
#pragma unroll
            for (int rr = 0; rr < 4; ++rr) {
                int rowi = bm + wr + mi * 16 + lg * 4 + rr;
                float v = acc[mi][ni][rr] + bv;
                if (relu) v = fmaxf(v, 0.f);
                size_t idx = (size_t)rowi * N + col;
                if (Cf) Cf[idx] = v;
                if (Cb) Cb[idx] = f2bf(v);
            }
        }
    }
}

// ---------------------------------------------------------------------------
// MFMA flash attention on fused QKV buffer [4096][1536] (q|k|v each 512).
// Block = 256 threads = 4 waves; each wave 16 q-rows (QBLK=64). KV chunks of
// 64 staged in LDS (K row-major, V transposed pair-packed). Fragments as in
// gemm128 (validated): A row=lane&15 k@(lane>>4)*8; B col=lane&15; C/D
// col=lane&15 row=(lane>>4)*4+reg. Rows padded to 72 ushorts.
// ---------------------------------------------------------------------------
__global__ __launch_bounds__(256) void attn_mfma(const ushort* __restrict__ QKV,
                                                 ushort* __restrict__ CTX) {
    __shared__ ushort Ks[64][72];
    __shared__ ushort VsT[64][72];
    __shared__ ushort Ps[4][16][72];

    int bid = blockIdx.x;
    int qt = bid & 31;             // 32 q-tiles of 64 rows
    int hh = (bid >> 5) & 7;
    int bb = bid >> 8;
    int q0 = qt * 64;
    int tid = threadIdx.x;
    int w = tid >> 6, l = tid & 63;
    int c = l & 15, g = l >> 4;

    size_t qbase = (size_t)bb * SS * QS + hh * DHH;
    size_t kbase = qbase + 512;
    size_t vbase = qbase + 1024;
    size_t obase = (size_t)bb * SS * DD + hh * DHH;

    short8 qf[2];
    {
        const ushort* qp = QKV + qbase + (size_t)(q0 + w * 16 + c) * QS + g * 8;
        qf[0] = *(const short8*)qp;
        qf[1] = *(const short8*)(qp + 32);
    }

    floatx4 O[4] = {};
    float mx[4] = {-1e30f, -1e30f, -1e30f, -1e30f};
    float dn[4] = {};

    for (int ch = 0; ch < SS; ch += 64) {
        __syncthreads();
        // K stage: row = tid>>2, dims (tid&3)*16..+15
        {
            int kk = tid >> 2, d0 = (tid & 3) * 16;
            const short8* gk = (const short8*)(QKV + kbase + (size_t)(ch + kk) * QS + d0);
            *(short8*)&Ks[kk][d0]     = gk[0];
            *(short8*)&Ks[kk][d0 + 8] = gk[1];
        }
        // V stage transposed pair-packed u32 (bank-checked: 2-way max)
        {
            int kp = (tid & 31) * 2, dv = (tid >> 5) * 8;
            const ushort* gv0 = QKV + vbase + (size_t)(ch + kp) * QS + dv;
            const ushort* gv1 = gv0 + QS;
            short8 va = *(const short8*)gv0;
            short8 vb = *(const short8*)gv1;
#pragma unroll
            for (int j = 0; j < 8; ++j) {
                unsigned int lo = (unsigned short)va[j], hi = (unsigned short)vb[j];
                *(unsigned int*)&VsT[dv + j][kp] = lo | (hi << 16);
            }
        }
        __syncthreads();

        // QK^T: 16q x 64k per wave
        floatx4 S[4] = {};
#pragma unroll
        for (int t = 0; t < 4; ++t) {
            short8 k0 = *(const short8*)&Ks[t * 16 + c][g * 8];
            short8 k1 = *(const short8*)&Ks[t * 16 + c][32 + g * 8];
            mfma16x16x32(S[t], qf[0], k0);
            mfma16x16x32(S[t], qf[1], k1);
        }

        // online softmax (1/8 scale folded into exp)
#pragma unroll
        for (int r = 0; r < 4; ++r) {
            float pm = fmaxf(fmaxf(S[0][r], S[1][r]), fmaxf(S[2][r], S[3][r]));
            pm = fmaxf(pm, __shfl_xor(pm, 1));
            pm = fmaxf(pm, __shfl_xor(pm, 2));
            pm = fmaxf(pm, __shfl_xor(pm, 4));
            pm = fmaxf(pm, __shfl_xor(pm, 8));
            float nmr = fmaxf(mx[r], pm);
            float scr = __expf((mx[r] - nmr) * 0.125f);
            float mb = -nmr * 0.125f;
            float e0 = __expf(fmaf(S[0][r], 0.125f, mb));
            float e1 = __expf(fmaf(S[1][r], 0.125f, mb));
            float e2 = __expf(fmaf(S[2][r], 0.125f, mb));
            float e3 = __expf(fmaf(S[3][r], 0.125f, mb));
            float ps = e0 + e1 + e2 + e3;
            ps += __shfl_xor(ps, 1);
            ps += __shfl_xor(ps, 2);
            ps += __shfl_xor(ps, 4);
            ps += __shfl_xor(ps, 8);
            dn[r] = dn[r] * scr + ps;
            mx[r] = nmr;
            O[0][r] *= scr; O[1][r] *= scr; O[2][r] *= scr; O[3][r] *= scr;
            int q = 4 * g + r;
            Ps[w][q][c]      = f2bf(e0);
            Ps[w][q][16 + c] = f2bf(e1);
            Ps[w][q][32 + c] = f2bf(e2);
            Ps[w][q][48 + c] = f2bf(e3);
        }

        // PV: O += P(16q x 64k) . V(64k x 64d)
#pragma unroll
        for (int s = 0; s < 2; ++s) {
            short8 pa = *(const short8*)&Ps[w][c][s * 32 + g * 8];
#pragma unroll
            for (int dt = 0; dt < 4; ++dt) {
                short8 vb = *(const short8*)&VsT[dt * 16 + c][s * 32 + g * 8];
                mfma16x16x32(O[dt], pa, vb);
            }
        }
    }

    float inv[4];
#pragma unroll
    for (int r = 0; r < 4; ++r) inv[r] = 1.f / dn[r];
#pragma unroll
    for (int dt = 0; dt < 4; ++dt) {
#pragma unroll
        for (int r = 0; r < 4; ++r) {
            size_t op = obase + (size_t)(q0 + w * 16 + 4 * g + r) * DD + dt * 16 + c;
            CTX[op] = f2bf(O[dt][r] * inv[r]);
        }
    }
}

// ---------------------------------------------------------------------------
// hout = LayerNorm(hin + yin) * g + b (fp32), plus bf16 copy to bout.
// ---------------------------------------------------------------------------
__global__ __launch_bounds__(256) void add_ln(const float* __restrict__ hin,
                                              const float* __restrict__ yin,
                                              const float* __restrict__ g,
                                              const float* __restrict__ b,
                                              float* __restrict__ hout,
                                              ushort* __restrict__ bout) {
    __shared__ float red[4];
    __shared__ float red2[4];
    int row = blockIdx.x, tid = threadIdx.x;
    const float* hr = hin + (size_t)row * DD;
    const float* yr = yin + (size_t)row * DD;
    float v0 = hr[tid] + yr[tid];
    float v1 = hr[tid + 256] + yr[tid + 256];
    float s = v0 + v1;
#pragma unroll
    for (int off = 32; off; off >>= 1) s += __shfl_xor(s, off);
    if ((tid & 63) == 0) red[tid >> 6] = s;
    __syncthreads();
    float mean = (red[0] + red[1] + red[2] + red[3]) * (1.f / 512.f);
    float d0 = v0 - mean, d1 = v1 - mean;
    float s2 = d0 * d0 + d1 * d1;
#pragma unroll
    for (int off = 32; off; off >>= 1) s2 += __shfl_xor(s2, off);
    if ((tid & 63) == 0) red2[tid >> 6] = s2;
    __syncthreads();
    float var = (red2[0] + red2[1] + red2[2] + red2[3]) * (1.f / 512.f);
    float rstd = rsqrtf(var + 1e-5f);
    float r0 = d0 * rstd * g[tid] + b[tid];
    float r1 = d1 * rstd * g[tid + 256] + b[tid + 256];
    float* ho = hout + (size_t)row * DD;
    ho[tid] = r0; ho[tid + 256] = r1;
    bout[(size_t)row * DD + tid] = f2bf(r0);
    bout[(size_t)row * DD + tid + 256] = f2bf(r1);
}

// ---------------------------------------------------------------------------
extern "C" void kernel_launch(void* const* d_in, const int* in_sizes, int n_in,
                              void* d_out, int out_size, void* d_ws, size_t ws_size,
                              hipStream_t stream) {
    const int*   x    = (const int*)d_in[0];
    const float* emb  = (const float*)d_in[1];
    const float* Wq   = (const float*)d_in[2];
    const float* bq   = (const float*)d_in[3];
    const float* Wk   = (const float*)d_in[4];
    const float* bk   = (const float*)d_in[5];
    const float* Wv   = (const float*)d_in[6];
    const float* bv   = (const float*)d_in[7];
    const float* Wo   = (const float*)d_in[8];
    const float* bo   = (const float*)d_in[9];
    const float* W1   = (const float*)d_in[10];
    const float* b1   = (const float*)d_in[11];
    const float* W2   = (const float*)d_in[12];
    const float* b2   = (const float*)d_in[13];
    const float* g1   = (const float*)d_in[14];
    const float* be1  = (const float*)d_in[15];
    const float* g2   = (const float*)d_in[16];
    const float* be2  = (const float*)d_in[17];
    float* out = (float*)d_out;

    char* ws = (char*)d_ws;
    size_t off = 0;
    auto alloc = [&](size_t bytes) -> void* {
        void* p = ws + off;
        off += (bytes + 255) & ~(size_t)255;
        return p;
    };
    float*  h    = (float*)alloc((size_t)NROWS * DD * 4);
    float*  y    = (float*)alloc((size_t)NROWS * DD * 4);
    ushort* hb   = (ushort*)alloc((size_t)NROWS * DD * 2);
    ushort* qkv  = (ushort*)alloc((size_t)NROWS * QS * 2);   // 12MB
    ushort* ctxb = (ushort*)alloc((size_t)NROWS * DD * 2);   // 4MB (adjacent)
    ushort* ff1  = qkv;   // FF1 [4096][2048] aliases dead qkv+ctxb (16MB)
    ushort* qkvT = (ushort*)alloc((size_t)6 * QS * DD * 2);
    ushort* WoT  = (ushort*)alloc((size_t)6 * DD * DD * 2);
    ushort* W1T  = (ushort*)alloc((size_t)6 * DD * 2048 * 2);
    ushort* W2T  = (ushort*)alloc((size_t)6 * DD * 2048 * 2);
    float*  qkvB = (float*)alloc((size_t)6 * QS * 4);

    if (ws_size < off) return;   // diagnostic guard (zeros signature)

    dim3 tb(32, 8);
    transpose_k<<<dim3(16, 16, 6), tb, 0, stream>>>(Wq, qkvT,              512, 512, QS * DD);
    transpose_k<<<dim3(16, 16, 6), tb, 0, stream>>>(Wk, qkvT + 512 * DD,   512, 512, QS * DD);
    transpose_k<<<dim3(16, 16, 6), tb, 0, stream>>>(Wv, qkvT + 1024 * DD,  512, 512, QS * DD);
    transpose_k<<<dim3(16, 16, 6), tb, 0, stream>>>(Wo, WoT,               512, 512, DD * DD);
    transpose_k<<<dim3(64, 16, 6), tb, 0, stream>>>(W1, W1T,  512, 2048, 2048 * DD);
    transpose_k<<<dim3(16, 64, 6), tb, 0, stream>>>(W2, W2T, 2048,  512, 2048 * DD);
    concat_bias<<<6, 512, 0, stream>>>(bq, bk, bv, qkvB);

    embed_pe<<<NROWS, 256, 0, stream>>>(x, emb, h, hb);

    for (int l = 0; l < 6; ++l) {
        gemm128<128><<<384, 256, 0, stream>>>(hb, qkvT + (size_t)l * QS * DD, qkvB + l * QS,
                                              nullptr, qkv, NROWS, QS, 512, 0);
        attn_mfma<<<512, 256, 0, stream>>>(qkv, ctxb);
        gemm128<64><<<256, 256, 0, stream>>>(ctxb, WoT + (size_t)l * DD * DD, bo + l * DD,
                                             y, nullptr, NROWS, DD, 512, 0);
        add_ln<<<NROWS, 256, 0, stream>>>(h, y, g1 + l * DD, be1 + l * DD, h, hb);
        gemm128<128><<<512, 256, 0, stream>>>(hb, W1T + (size_t)l * 2048 * DD, b1 + l * 2048,
                                              nullptr, ff1, NROWS, 2048, 512, 1);
        gemm128<64><<<256, 256, 0, stream>>>(ff1, W2T + (size_t)l * 2048 * DD, b2 + l * DD,
                                             y, nullptr, NROWS, DD, 2048, 0);
        add_ln<<<NROWS, 256, 0, stream>>>(h, y, g2 + l * DD, be2 + l * DD,
                                          (l == 5) ? out : h, hb);
    }
}

// Round 6
// 973.955 us; speedup vs baseline: 6.7798x; 1.1405x over previous
//
#include <hip/hip_runtime.h>
#include <hip/hip_bf16.h>

// ---------------------------------------------------------------------------
// TransformerEncoder: B=2, S=2048, D=512, H=8, DH=64, DF=2048, NX=6 layers
// I/O fp32. bf16 MFMA GEMMs (128-tile, 2-phase double-buffered pipeline),
// fused QKV, 4-wave MFMA flash attention (KVBLK=128, reg-prefetch),
// fp32 residual + single-pass LayerNorm.
// ---------------------------------------------------------------------------

typedef __attribute__((ext_vector_type(4))) float  floatx4;
typedef __attribute__((ext_vector_type(8))) short  short8;
typedef __bf16 bf16x8 __attribute__((ext_vector_type(8)));

#define SS 2048
#define DD 512
#define HH 8
#define DHH 64
#define NROWS 4096   /* B*S */
#define QS 1536      /* fused qkv row stride */

__device__ __forceinline__ float bf2f(unsigned short u) {
    union { float f; unsigned int i; } x; x.i = ((unsigned int)u) << 16; return x.f;
}
__device__ __forceinline__ unsigned short f2bf(float f) {
    union { float f; unsigned int i; } x; x.f = f;
    unsigned int lsb = (x.i >> 16) & 1u;
    x.i += 0x7fffu + lsb;
    return (unsigned short)(x.i >> 16);
}
// round-half-up, for positive finite values (softmax P) — 2 ops
__device__ __forceinline__ unsigned short f2bf_fast(float f) {
    union { float f; unsigned int i; } x; x.f = f;
    return (unsigned short)((x.i + 0x8000u) >> 16);
}

#if __has_builtin(__builtin_amdgcn_mfma_f32_16x16x32_bf16)
__device__ __forceinline__ void mfma16x16x32(floatx4& d, short8 a, short8 b) {
    bf16x8 ab, bb;
    __builtin_memcpy(&ab, &a, 16);
    __builtin_memcpy(&bb, &b, 16);
    d = __builtin_amdgcn_mfma_f32_16x16x32_bf16(ab, bb, d, 0, 0, 0);
}
#else
__device__ __forceinline__ void mfma16x16x32(floatx4& d, short8 a, short8 b) {
    asm volatile("s_nop 1\n\t"
                 "v_mfma_f32_16x16x32_bf16 %0, %1, %2, %0\n\t"
                 "s_nop 7\n\t"
                 "s_nop 7"
                 : "+v"(d) : "v"(a), "v"(b));
}
#endif

// stage 16B/lane: g = per-lane global src, lbase = wave-uniform LDS chunk base,
// HW writes lbase + lane*16.
#if __has_builtin(__builtin_amdgcn_global_load_lds)
__device__ __forceinline__ void stage16(const ushort* g, ushort* lbase, int lane) {
    __builtin_amdgcn_global_load_lds(
        (const __attribute__((address_space(1))) unsigned int*)g,
        (__attribute__((address_space(3))) unsigned int*)lbase, 16, 0, 0);
}
#else
__device__ __forceinline__ void stage16(const ushort* g, ushort* lbase, int lane) {
    *(short8*)(lbase + lane * 8) = *(const short8*)g;
}
#endif

// ---------------------------------------------------------------------------
// Weight transpose + fp32->bf16: W [z][R][C] fp32 -> dst [z*zstride + C*R] bf16
// ---------------------------------------------------------------------------
__global__ __launch_bounds__(256) void transpose_k(const float* __restrict__ W,
                                                   ushort* __restrict__ WT,
                                                   int R, int C, int zstride) {
    __shared__ ushort t[32][33];
    int z = blockIdx.z;
    const float* Wz = W + (size_t)z * R * C;
    ushort* WTz = WT + (size_t)z * zstride;
    int c0 = blockIdx.x * 32, r0 = blockIdx.y * 32;
    int x = threadIdx.x, y = threadIdx.y;         // (32,8)
#pragma unroll
    for (int i = 0; i < 32; i += 8)
        t[y + i][x] = f2bf(Wz[(size_t)(r0 + y + i) * C + c0 + x]);
    __syncthreads();
#pragma unroll
    for (int i = 0; i < 32; i += 8)
        WTz[(size_t)(c0 + y + i) * R + r0 + x] = t[x][y + i];
}

__global__ __launch_bounds__(512) void concat_bias(const float* __restrict__ bq,
                                                   const float* __restrict__ bk,
                                                   const float* __restrict__ bv,
                                                   float* __restrict__ qkvB) {
    int l = blockIdx.x, t = threadIdx.x;
    qkvB[l * QS + t]        = bq[l * DD + t];
    qkvB[l * QS + 512 + t]  = bk[l * DD + t];
    qkvB[l * QS + 1024 + t] = bv[l * DD + t];
}

// ---------------------------------------------------------------------------
// Embedding + positional encoding.
// ---------------------------------------------------------------------------
__global__ __launch_bounds__(256) void embed_pe(const int* __restrict__ x,
                                                const float* __restrict__ emb,
                                                float* __restrict__ h,
                                                ushort* __restrict__ hb) {
    __shared__ int isI32;
    int row = blockIdx.x, tid = threadIdx.x;
    if (tid == 0) isI32 = 0;
    __syncthreads();
    int acc = 0;
    for (int i = tid; i < 2048; i += 256) acc |= x[2 * i + 1];
    if (acc) isI32 = 1;
    __syncthreads();
    int tok = isI32 ? x[row] : x[2 * row];
    int s = row & (SS - 1);
    const float* er = emb + (size_t)tok * DD;
    for (int c = tid; c < DD; c += 256) {
        float e = er[c] * 22.62741699796952f;              // sqrt(512)
        float freq = __expf(-((float)c * (1.f / 256.f)) * 9.210340371976184f);
        float ang = (float)s * freq;
        float pe = (c & 1) ? cosf(ang) : sinf(ang);
        float val = e + pe;
        h[(size_t)row * DD + c] = val;
        hb[(size_t)row * DD + c] = f2bf(val);
    }
}

// ---------------------------------------------------------------------------
// 2-phase pipelined GEMM: C[M,N] = A[M,K] @ BT[N,K]^T + bias. BM=128, BK=32,
// double-buffered LDS, ONE barrier per K-step, next-tile global_load_lds
// issued before current ds_read+MFMA (loads hide under compute).
// BN=128: waves 2x2, acc 4x4.  BN=64: waves 4x1, acc 2x4.
// ---------------------------------------------------------------------------
template <int BN>
__global__ __launch_bounds__(256) void gemm128(const ushort* __restrict__ A,
                                               const ushort* __restrict__ BT,
                                               const float* __restrict__ bias,
                                               float* __restrict__ Cf,
                                               ushort* __restrict__ Cb,
                                               int M, int N, int K, int relu) {
    constexpr int MI = (BN == 128) ? 4 : 2;
    constexpr int NI = 4;
    __shared__ ushort As[2][128 * 32];
    __shared__ ushort Bs[2][BN * 32];

    int bid = blockIdx.x;
    int nbn = N / BN;
    int bm = (bid / nbn) * 128;
    int bn = (bid % nbn) * BN;
    int tid = threadIdx.x;
    int lane = tid & 63, w = tid >> 6;
    int lr = lane & 15, lg = lane >> 4;

    // staging: chunk = 16 rows x 32 cols = 1KB; lane -> (row=lane>>2, col=(lane&3)*8)
    int srow = lane >> 2, scol = (lane & 3) * 8;
    const ushort* gA0 = A + (size_t)(bm + w * 32 + srow) * K + scol;
    const ushort* gA1 = gA0 + (size_t)16 * K;
    const ushort* gB0;
    const ushort* gB1 = nullptr;
    if (BN == 128) {
        gB0 = BT + (size_t)(bn + w * 32 + srow) * K + scol;
        gB1 = gB0 + (size_t)16 * K;
    } else {
        gB0 = BT + (size_t)(bn + w * 16 + srow) * K + scol;
    }
    int aoff0 = (w * 2 + 0) * 512, aoff1 = (w * 2 + 1) * 512;
    int boff0 = (BN == 128) ? (w * 2 + 0) * 512 : w * 512;
    int boff1 = (w * 2 + 1) * 512;

    int wr = (BN == 128) ? (w >> 1) * 64 : w * 32;
    int wc = (BN == 128) ? (w & 1) * 64 : 0;

    floatx4 acc[MI][NI] = {};
    int T = K >> 5;

    // prologue: stage tile 0 into buffer 0
    stage16(gA0, &As[0][aoff0], lane);
    stage16(gA1, &As[0][aoff1], lane);
    stage16(gB0, &Bs[0][boff0], lane);
    if (BN == 128) stage16(gB1, &Bs[0][boff1], lane);
    __syncthreads();

    for (int t = 0; t < T; ++t) {
        int cur = t & 1;
        if (t + 1 < T) {               // issue next-tile loads (overlap compute)
            int ko = (t + 1) * 32;
            stage16(gA0 + ko, &As[cur ^ 1][aoff0], lane);
            stage16(gA1 + ko, &As[cur ^ 1][aoff1], lane);
            stage16(gB0 + ko, &Bs[cur ^ 1][boff0], lane);
            if (BN == 128) stage16(gB1 + ko, &Bs[cur ^ 1][boff1], lane);
        }
        short8 af[MI], bf[NI];
#pragma unroll
        for (int mi = 0; mi < MI; ++mi)
            af[mi] = *(const short8*)&As[cur][(wr + mi * 16 + lr) * 32 + lg * 8];
#pragma unroll
        for (int ni = 0; ni < NI; ++ni)
            bf[ni] = *(const short8*)&Bs[cur][(wc + ni * 16 + lr) * 32 + lg * 8];
#pragma unroll
        for (int mi = 0; mi < MI; ++mi)
#pragma unroll
            for (int ni = 0; ni < NI; ++ni)
                mfma16x16x32(acc[mi][ni], af[mi], bf[ni]);
        if (t + 1 < T) __syncthreads();   // drains vmcnt+lgkmcnt: next tile ready,
                                          // all waves done reading buf[cur]
    }

#pragma unroll
    for (int ni = 0; ni < NI; ++ni) {
        int col = bn + wc + ni * 16 + lr;
        float bv = bias[col];
#pragma unroll
        for (int mi = 0; mi < MI; ++mi) {
#pragma unroll
            for (int rr = 0; rr < 4; ++rr) {
                int rowi = bm + wr + mi * 16 + lg * 4 + rr;
                float v = acc[mi][ni][rr] + bv;
                if (relu) v = fmaxf(v, 0.f);
                size_t idx = (size_t)rowi * N + col;
                if (Cf) Cf[idx] = v;
                if (Cb) Cb[idx] = f2bf(v);
            }
        }
    }
}

// ---------------------------------------------------------------------------
// MFMA flash attention, fused QKV input [4096][1536]. 256 threads = 4 waves,
// each wave 16 q-rows (QBLK=64). KVBLK=128 staged in LDS (K row-major padded,
// V transposed pair-packed); next chunk prefetched into registers during
// compute. 1/8 scale folded into Q (exact). Fragments as gemm128.
// ---------------------------------------------------------------------------
__global__ __launch_bounds__(256) void attn_mfma(const ushort* __restrict__ QKV,
                                                 ushort* __restrict__ CTX) {
    __shared__ ushort Ks[128][72];
    __shared__ ushort VsT[64][136];
    __shared__ ushort Ps[4][16][136];

    int bid = blockIdx.x;
    int qt = bid & 31;             // 32 q-tiles of 64 rows
    int hh = (bid >> 5) & 7;
    int bb = bid >> 8;
    int q0 = qt * 64;
    int tid = threadIdx.x;
    int w = tid >> 6, l = tid & 63;
    int c = l & 15, g = l >> 4;

    size_t qbase = (size_t)bb * SS * QS + hh * DHH;
    size_t kbase = qbase + 512;
    size_t vbase = qbase + 1024;
    size_t obase = (size_t)bb * SS * DD + hh * DHH;

    // Q fragments, scaled by 1/8 (exact in bf16)
    short8 qf[2];
    {
        const ushort* qp = QKV + qbase + (size_t)(q0 + w * 16 + c) * QS + g * 8;
        short8 q0v = *(const short8*)qp;
        short8 q1v = *(const short8*)(qp + 32);
#pragma unroll
        for (int j = 0; j < 8; ++j) {
            q0v[j] = (short)f2bf(bf2f((unsigned short)q0v[j]) * 0.125f);
            q1v[j] = (short)f2bf(bf2f((unsigned short)q1v[j]) * 0.125f);
        }
        qf[0] = q0v; qf[1] = q1v;
    }

    // K prefetch regs: row kk=tid>>1, 32 dims at (tid&1)*32
    int kk = tid >> 1, kd0 = (tid & 1) * 32;
    // V prefetch regs: key pair kp=(tid&63)*2, 16 dims at (tid>>6)*16
    int kp = (tid & 63) * 2, dv = (tid >> 6) * 16;

    short8 kreg[4], vreg[4];
    {
        const short8* gk = (const short8*)(QKV + kbase + (size_t)kk * QS + kd0);
        kreg[0] = gk[0]; kreg[1] = gk[1]; kreg[2] = gk[2]; kreg[3] = gk[3];
        const ushort* gv0 = QKV + vbase + (size_t)kp * QS + dv;
        vreg[0] = *(const short8*)gv0;
        vreg[1] = *(const short8*)(gv0 + 8);
        vreg[2] = *(const short8*)(gv0 + QS);
        vreg[3] = *(const short8*)(gv0 + QS + 8);
    }

    floatx4 O[4] = {};
    float mx[4] = {-1e30f, -1e30f, -1e30f, -1e30f};
    float dn[4] = {};

    for (int ch = 0; ch < SS; ch += 128) {
        __syncthreads();    // prev chunk's readers done; prefetch loads drained
        // write prefetched K/V regs to LDS
        *(short8*)&Ks[kk][kd0]      = kreg[0];
        *(short8*)&Ks[kk][kd0 + 8]  = kreg[1];
        *(short8*)&Ks[kk][kd0 + 16] = kreg[2];
        *(short8*)&Ks[kk][kd0 + 24] = kreg[3];
#pragma unroll
        for (int j = 0; j < 8; ++j) {
            unsigned int lo = (unsigned short)vreg[0][j], hi = (unsigned short)vreg[2][j];
            *(unsigned int*)&VsT[dv + j][kp] = lo | (hi << 16);
        }
#pragma unroll
        for (int j = 0; j < 8; ++j) {
            unsigned int lo = (unsigned short)vreg[1][j], hi = (unsigned short)vreg[3][j];
            *(unsigned int*)&VsT[dv + 8 + j][kp] = lo | (hi << 16);
        }
        __syncthreads();    // Ks/VsT ready

        // prefetch next chunk into regs (lands during compute below)
        if (ch + 128 < SS) {
            const short8* gk = (const short8*)(QKV + kbase + (size_t)(ch + 128 + kk) * QS + kd0);
            kreg[0] = gk[0]; kreg[1] = gk[1]; kreg[2] = gk[2]; kreg[3] = gk[3];
            const ushort* gv0 = QKV + vbase + (size_t)(ch + 128 + kp) * QS + dv;
            vreg[0] = *(const short8*)gv0;
            vreg[1] = *(const short8*)(gv0 + 8);
            vreg[2] = *(const short8*)(gv0 + QS);
            vreg[3] = *(const short8*)(gv0 + QS + 8);
        }

        // QK^T: 16q x 128k per wave (8 key-tiles)
        floatx4 S[8];
#pragma unroll
        for (int t = 0; t < 8; ++t) {
            floatx4 z = {};
            short8 k0 = *(const short8*)&Ks[t * 16 + c][g * 8];
            short8 k1 = *(const short8*)&Ks[t * 16 + c][32 + g * 8];
            mfma16x16x32(z, qf[0], k0);
            mfma16x16x32(z, qf[1], k1);
            S[t] = z;
        }

        // online softmax (scores pre-scaled via Q)
#pragma unroll
        for (int r = 0; r < 4; ++r) {
            float pm = fmaxf(fmaxf(fmaxf(S[0][r], S[1][r]), fmaxf(S[2][r], S[3][r])),
                             fmaxf(fmaxf(S[4][r], S[5][r]), fmaxf(S[6][r], S[7][r])));
            pm = fmaxf(pm, __shfl_xor(pm, 1));
            pm = fmaxf(pm, __shfl_xor(pm, 2));
            pm = fmaxf(pm, __shfl_xor(pm, 4));
            pm = fmaxf(pm, __shfl_xor(pm, 8));
            float nmr = fmaxf(mx[r], pm);
            float scr = __expf(mx[r] - nmr);
            float e[8];
            float ps = 0.f;
#pragma unroll
            for (int t = 0; t < 8; ++t) {
                e[t] = __expf(S[t][r] - nmr);
                ps += e[t];
            }
            ps += __shfl_xor(ps, 1);
            ps += __shfl_xor(ps, 2);
            ps += __shfl_xor(ps, 4);
            ps += __shfl_xor(ps, 8);
            dn[r] = dn[r] * scr + ps;
            mx[r] = nmr;
            O[0][r] *= scr; O[1][r] *= scr; O[2][r] *= scr; O[3][r] *= scr;
            int q = 4 * g + r;
#pragma unroll
            for (int t = 0; t < 8; ++t)
                Ps[w][q][t * 16 + c] = f2bf_fast(e[t]);
        }

        // PV: O += P(16q x 128k) . V(128k x 64d)
#pragma unroll
        for (int s = 0; s < 4; ++s) {
            short8 pa = *(const short8*)&Ps[w][c][s * 32 + g * 8];
#pragma unroll
            for (int dt = 0; dt < 4; ++dt) {
                short8 vb = *(const short8*)&VsT[dt * 16 + c][s * 32 + g * 8];
                mfma16x16x32(O[dt], pa, vb);
            }
        }
    }

    float inv[4];
#pragma unroll
    for (int r = 0; r < 4; ++r) inv[r] = 1.f / dn[r];
#pragma unroll
    for (int dt = 0; dt < 4; ++dt) {
#pragma unroll
        for (int r = 0; r < 4; ++r) {
            size_t op = obase + (size_t)(q0 + w * 16 + 4 * g + r) * DD + dt * 16 + c;
            CTX[op] = f2bf(O[dt][r] * inv[r]);
        }
    }
}

// ---------------------------------------------------------------------------
// hout = LayerNorm(hin + yin) * g + b. 128 threads per 512-row, float4 loads,
// single-pass mean/var (E[x^2]-mu^2). Optional bf16 copy.
// ---------------------------------------------------------------------------
__global__ __launch_bounds__(128) void add_ln(const float* __restrict__ hin,
                                              const float* __restrict__ yin,
                                              const float* __restrict__ g,
                                              const float* __restrict__ b,
                                              float* __restrict__ hout,
                                              ushort* __restrict__ bout) {
    __shared__ float sh[4];
    int row = blockIdx.x, tid = threadIdx.x;    // 0..127
    const float4 hv = ((const float4*)(hin + (size_t)row * DD))[tid];
    const float4 yv = ((const float4*)(yin + (size_t)row * DD))[tid];
    float4 v;
    v.x = hv.x + yv.x; v.y = hv.y + yv.y; v.z = hv.z + yv.z; v.w = hv.w + yv.w;
    float s = v.x + v.y + v.z + v.w;
    float q = v.x * v.x + v.y * v.y + v.z * v.z + v.w * v.w;
#pragma unroll
    for (int off = 32; off; off >>= 1) {
        s += __shfl_xor(s, off);
        q += __shfl_xor(q, off);
    }
    int wv = tid >> 6;
    if ((tid & 63) == 0) { sh[wv * 2] = s; sh[wv * 2 + 1] = q; }
    __syncthreads();
    float St = sh[0] + sh[2], Qt = sh[1] + sh[3];
    float mean = St * (1.f / 512.f);
    float var = Qt * (1.f / 512.f) - mean * mean;
    float rstd = rsqrtf(var + 1e-5f);
    const float4 gv = ((const float4*)g)[tid];
    const float4 bv = ((const float4*)b)[tid];
    float4 r;
    r.x = (v.x - mean) * rstd * gv.x + bv.x;
    r.y = (v.y - mean) * rstd * gv.y + bv.y;
    r.z = (v.z - mean) * rstd * gv.z + bv.z;
    r.w = (v.w - mean) * rstd * gv.w + bv.w;
    ((float4*)(hout + (size_t)row * DD))[tid] = r;
    if (bout) {
        union { ushort u[4]; unsigned long long ll; } pk;
        pk.u[0] = f2bf(r.x); pk.u[1] = f2bf(r.y);
        pk.u[2] = f2bf(r.z); pk.u[3] = f2bf(r.w);
        *(unsigned long long*)(bout + (size_t)row * DD + tid * 4) = pk.ll;
    }
}

// ---------------------------------------------------------------------------
extern "C" void kernel_launch(void* const* d_in, const int* in_sizes, int n_in,
                              void* d_out, int out_size, void* d_ws, size_t ws_size,
                              hipStream_t stream) {
    const int*   x    = (const int*)d_in[0];
    const float* emb  = (const float*)d_in[1];
    const float* Wq   = (const float*)d_in[2];
    const float* bq   = (const float*)d_in[3];
    const float* Wk   = (const float*)d_in[4];
    const float* bk   = (const float*)d_in[5];
    const float* Wv   = (const float*)d_in[6];
    const float* bv   = (const float*)d_in[7];
    const float* Wo   = (const float*)d_in[8];
    const float* bo   = (const float*)d_in[9];
    const float* W1   = (const float*)d_in[10];
    const float* b1   = (const float*)d_in[11];
    const float* W2   = (const float*)d_in[12];
    const float* b2   = (const float*)d_in[13];
    const float* g1   = (const float*)d_in[14];
    const float* be1  = (const float*)d_in[15];
    const float* g2   = (const float*)d_in[16];
    const float* be2  = (const float*)d_in[17];
    float* out = (float*)d_out;

    char* ws = (char*)d_ws;
    size_t off = 0;
    auto alloc = [&](size_t bytes) -> void* {
        void* p = ws + off;
        off += (bytes + 255) & ~(size_t)255;
        return p;
    };
    float*  h    = (float*)alloc((size_t)NROWS * DD * 4);
    float*  y    = (float*)alloc((size_t)NROWS * DD * 4);
    ushort* hb   = (ushort*)alloc((size_t)NROWS * DD * 2);
    ushort* qkv  = (ushort*)alloc((size_t)NROWS * QS * 2);   // 12MB
    ushort* ctxb = (ushort*)alloc((size_t)NROWS * DD * 2);   // 4MB (adjacent)
    ushort* ff1  = qkv;   // FF1 [4096][2048] aliases dead qkv+ctxb (16MB)
    ushort* qkvT = (ushort*)alloc((size_t)6 * QS * DD * 2);
    ushort* WoT  = (ushort*)alloc((size_t)6 * DD * DD * 2);
    ushort* W1T  = (ushort*)alloc((size_t)6 * DD * 2048 * 2);
    ushort* W2T  = (ushort*)alloc((size_t)6 * DD * 2048 * 2);
    float*  qkvB = (float*)alloc((size_t)6 * QS * 4);

    if (ws_size < off) return;   // diagnostic guard (zeros signature)

    dim3 tb(32, 8);
    transpose_k<<<dim3(16, 16, 6), tb, 0, stream>>>(Wq, qkvT,              512, 512, QS * DD);
    transpose_k<<<dim3(16, 16, 6), tb, 0, stream>>>(Wk, qkvT + 512 * DD,   512, 512, QS * DD);
    transpose_k<<<dim3(16, 16, 6), tb, 0, stream>>>(Wv, qkvT + 1024 * DD,  512, 512, QS * DD);
    transpose_k<<<dim3(16, 16, 6), tb, 0, stream>>>(Wo, WoT,               512, 512, DD * DD);
    transpose_k<<<dim3(64, 16, 6), tb, 0, stream>>>(W1, W1T,  512, 2048, 2048 * DD);
    transpose_k<<<dim3(16, 64, 6), tb, 0, stream>>>(W2, W2T, 2048,  512, 2048 * DD);
    concat_bias<<<6, 512, 0, stream>>>(bq, bk, bv, qkvB);

    embed_pe<<<NROWS, 256, 0, stream>>>(x, emb, h, hb);

    for (int l = 0; l < 6; ++l) {
        gemm128<128><<<384, 256, 0, stream>>>(hb, qkvT + (size_t)l * QS * DD, qkvB + l * QS,
                                              nullptr, qkv, NROWS, QS, 512, 0);
        attn_mfma<<<512, 256, 0, stream>>>(qkv, ctxb);
        gemm128<64><<<256, 256, 0, stream>>>(ctxb, WoT + (size_t)l * DD * DD, bo + l * DD,
                                             y, nullptr, NROWS, DD, 512, 0);
        add_ln<<<NROWS, 128, 0, stream>>>(h, y, g1 + l * DD, be1 + l * DD, h, hb);
        gemm128<128><<<512, 256, 0, stream>>>(hb, W1T + (size_t)l * 2048 * DD, b1 + l * 2048,
                                              nullptr, ff1, NROWS, 2048, 512, 1);
        gemm128<64><<<256, 256, 0, stream>>>(ff1, W2T + (size_t)l * 2048 * DD, b2 + l * DD,
                                             y, nullptr, NROWS, DD, 2048, 0);
        add_ln<<<NROWS, 128, 0, stream>>>(h, y, g2 + l * DD, be2 + l * DD,
                                          (l == 5) ? out : h, (l == 5) ? nullptr : hb);
    }
}

// Round 7
// 892.262 us; speedup vs baseline: 7.4006x; 1.0916x over previous
//
#include <hip/hip_runtime.h>
#include <hip/hip_bf16.h>

// ---------------------------------------------------------------------------
// TransformerEncoder: B=2, S=2048, D=512, H=8, DH=64, DF=2048, NX=6 layers
// I/O fp32. bf16 MFMA GEMMs (128-tile, 2-phase double-buffered, XCD-swizzled,
// split-K for the N=512 GEMMs), fused QKV, 8-wave MFMA flash attention
// (QBLK=128, KVBLK=128, reg-prefetch, setprio), fp32 residual + LayerNorm.
// ---------------------------------------------------------------------------

typedef __attribute__((ext_vector_type(4))) float  floatx4;
typedef __attribute__((ext_vector_type(8))) short  short8;
typedef __bf16 bf16x8 __attribute__((ext_vector_type(8)));

#define SS 2048
#define DD 512
#define HH 8
#define DHH 64
#define NROWS 4096   /* B*S */
#define QS 1536      /* fused qkv row stride */

__device__ __forceinline__ float bf2f(unsigned short u) {
    union { float f; unsigned int i; } x; x.i = ((unsigned int)u) << 16; return x.f;
}
__device__ __forceinline__ unsigned short f2bf(float f) {
    union { float f; unsigned int i; } x; x.f = f;
    unsigned int lsb = (x.i >> 16) & 1u;
    x.i += 0x7fffu + lsb;
    return (unsigned short)(x.i >> 16);
}
// round-half-up for positive finite values (softmax P)
__device__ __forceinline__ unsigned short f2bf_fast(float f) {
    union { float f; unsigned int i; } x; x.f = f;
    return (unsigned short)((x.i + 0x8000u) >> 16);
}

#if __has_builtin(__builtin_amdgcn_mfma_f32_16x16x32_bf16)
__device__ __forceinline__ void mfma16x16x32(floatx4& d, short8 a, short8 b) {
    bf16x8 ab, bb;
    __builtin_memcpy(&ab, &a, 16);
    __builtin_memcpy(&bb, &b, 16);
    d = __builtin_amdgcn_mfma_f32_16x16x32_bf16(ab, bb, d, 0, 0, 0);
}
#else
__device__ __forceinline__ void mfma16x16x32(floatx4& d, short8 a, short8 b) {
    asm volatile("s_nop 1\n\t"
                 "v_mfma_f32_16x16x32_bf16 %0, %1, %2, %0\n\t"
                 "s_nop 7\n\t"
                 "s_nop 7"
                 : "+v"(d) : "v"(a), "v"(b));
}
#endif

// stage 16B/lane: g = per-lane global src, lbase = wave-uniform LDS chunk base
#if __has_builtin(__builtin_amdgcn_global_load_lds)
__device__ __forceinline__ void stage16(const ushort* g, ushort* lbase, int lane) {
    __builtin_amdgcn_global_load_lds(
        (const __attribute__((address_space(1))) unsigned int*)g,
        (__attribute__((address_space(3))) unsigned int*)lbase, 16, 0, 0);
}
#else
__device__ __forceinline__ void stage16(const ushort* g, ushort* lbase, int lane) {
    *(short8*)(lbase + lane * 8) = *(const short8*)g;
}
#endif

// ---------------------------------------------------------------------------
// Weight transpose + fp32->bf16: W [z][R][C] fp32 -> dst [z*zstride + C*R] bf16
// ---------------------------------------------------------------------------
__global__ __launch_bounds__(256) void transpose_k(const float* __restrict__ W,
                                                   ushort* __restrict__ WT,
                                                   int R, int C, int zstride) {
    __shared__ ushort t[32][33];
    int z = blockIdx.z;
    const float* Wz = W + (size_t)z * R * C;
    ushort* WTz = WT + (size_t)z * zstride;
    int c0 = blockIdx.x * 32, r0 = blockIdx.y * 32;
    int x = threadIdx.x, y = threadIdx.y;         // (32,8)
#pragma unroll
    for (int i = 0; i < 32; i += 8)
        t[y + i][x] = f2bf(Wz[(size_t)(r0 + y + i) * C + c0 + x]);
    __syncthreads();
#pragma unroll
    for (int i = 0; i < 32; i += 8)
        WTz[(size_t)(c0 + y + i) * R + r0 + x] = t[x][y + i];
}

__global__ __launch_bounds__(512) void concat_bias(const float* __restrict__ bq,
                                                   const float* __restrict__ bk,
                                                   const float* __restrict__ bv,
                                                   float* __restrict__ qkvB) {
    int l = blockIdx.x, t = threadIdx.x;
    qkvB[l * QS + t]        = bq[l * DD + t];
    qkvB[l * QS + 512 + t]  = bk[l * DD + t];
    qkvB[l * QS + 1024 + t] = bv[l * DD + t];
}

// ---------------------------------------------------------------------------
// Embedding + positional encoding.
// ---------------------------------------------------------------------------
__global__ __launch_bounds__(256) void embed_pe(const int* __restrict__ x,
                                                const float* __restrict__ emb,
                                                float* __restrict__ h,
                                                ushort* __restrict__ hb) {
    __shared__ int isI32;
    int row = blockIdx.x, tid = threadIdx.x;
    if (tid == 0) isI32 = 0;
    __syncthreads();
    int acc = 0;
    for (int i = tid; i < 2048; i += 256) acc |= x[2 * i + 1];
    if (acc) isI32 = 1;
    __syncthreads();
    int tok = isI32 ? x[row] : x[2 * row];
    int s = row & (SS - 1);
    const float* er = emb + (size_t)tok * DD;
    for (int c = tid; c < DD; c += 256) {
        float e = er[c] * 22.62741699796952f;              // sqrt(512)
        float freq = __expf(-((float)c * (1.f / 256.f)) * 9.210340371976184f);
        float ang = (float)s * freq;
        float pe = (c & 1) ? cosf(ang) : sinf(ang);
        float val = e + pe;
        h[(size_t)row * DD + c] = val;
        hb[(size_t)row * DD + c] = f2bf(val);
    }
}

// ---------------------------------------------------------------------------
// 2-phase pipelined GEMM. BM=128, BN=128, BK=32, double-buffered LDS, one
// barrier per K-step, next-tile global_load_lds issued before ds_read+MFMA.
// XCD-bijective swizzle (grid%8==0). Optional split-K (SPLITK blocks along K;
// ks=0 adds bias -> Cf/Cb, ks=1 raw partial -> Cf2; relu only valid splitk=1).
// ---------------------------------------------------------------------------
__global__ __launch_bounds__(256) void gemm128(const ushort* __restrict__ A,
                                               const ushort* __restrict__ BT,
                                               const float* __restrict__ bias,
                                               float* __restrict__ Cf,
                                               ushort* __restrict__ Cb,
                                               float* __restrict__ Cf2,
                                               int M, int N, int K,
                                               int relu, int splitk) {
    constexpr int MI = 4, NI = 4;
    __shared__ ushort As[2][128 * 32];
    __shared__ ushort Bs[2][128 * 32];

    int nwg = gridDim.x;
    int raw = blockIdx.x;
    int bs = (raw & 7) * (nwg >> 3) + (raw >> 3);   // XCD co-locate
    int kblocks = nwg / splitk;
    int ks = bs / kblocks;
    int tb = bs - ks * kblocks;
    int Keff = K / splitk;
    int kofs = ks * Keff;

    int nbn = N >> 7;
    int bm = (tb / nbn) << 7;
    int bn = (tb % nbn) << 7;
    int tid = threadIdx.x;
    int lane = tid & 63, w = tid >> 6;
    int lr = lane & 15, lg = lane >> 4;

    // staging: chunk = 16 rows x 32 cols = 1KB; lane -> (row=lane>>2, col=(lane&3)*8)
    int srow = lane >> 2, scol = (lane & 3) * 8;
    const ushort* gA0 = A + (size_t)(bm + w * 32 + srow) * K + kofs + scol;
    const ushort* gA1 = gA0 + (size_t)16 * K;
    const ushort* gB0 = BT + (size_t)(bn + w * 32 + srow) * K + kofs + scol;
    const ushort* gB1 = gB0 + (size_t)16 * K;
    int aoff0 = (w * 2 + 0) * 512, aoff1 = (w * 2 + 1) * 512;

    int wr = (w >> 1) * 64;
    int wc = (w & 1) * 64;

    floatx4 acc[MI][NI] = {};
    int T = Keff >> 5;

    stage16(gA0, &As[0][aoff0], lane);
    stage16(gA1, &As[0][aoff1], lane);
    stage16(gB0, &Bs[0][aoff0], lane);
    stage16(gB1, &Bs[0][aoff1], lane);
    __syncthreads();

    for (int t = 0; t < T; ++t) {
        int cur = t & 1;
        if (t + 1 < T) {               // issue next-tile loads (overlap compute)
            int ko = (t + 1) * 32;
            stage16(gA0 + ko, &As[cur ^ 1][aoff0], lane);
            stage16(gA1 + ko, &As[cur ^ 1][aoff1], lane);
            stage16(gB0 + ko, &Bs[cur ^ 1][aoff0], lane);
            stage16(gB1 + ko, &Bs[cur ^ 1][aoff1], lane);
        }
        short8 af[MI], bf[NI];
#pragma unroll
        for (int mi = 0; mi < MI; ++mi)
            af[mi] = *(const short8*)&As[cur][(wr + mi * 16 + lr) * 32 + lg * 8];
#pragma unroll
        for (int ni = 0; ni < NI; ++ni)
            bf[ni] = *(const short8*)&Bs[cur][(wc + ni * 16 + lr) * 32 + lg * 8];
#pragma unroll
        for (int mi = 0; mi < MI; ++mi)
#pragma unroll
            for (int ni = 0; ni < NI; ++ni)
                mfma16x16x32(acc[mi][ni], af[mi], bf[ni]);
        if (t + 1 < T) __syncthreads();
    }

#pragma unroll
    for (int ni = 0; ni < NI; ++ni) {
        int col = bn + wc + ni * 16 + lr;
        float bv = ks ? 0.f : bias[col];
#pragma unroll
        for (int mi = 0; mi < MI; ++mi) {
#pragma unroll
            for (int rr = 0; rr < 4; ++rr) {
                int rowi = bm + wr + mi * 16 + lg * 4 + rr;
                float v = acc[mi][ni][rr] + bv;
                if (relu) v = fmaxf(v, 0.f);
                size_t idx = (size_t)rowi * N + col;
                if (ks) { Cf2[idx] = v; }
                else {
                    if (Cf) Cf[idx] = v;
                    if (Cb) Cb[idx] = f2bf(v);
                }
            }
        }
    }
}

// ---------------------------------------------------------------------------
// MFMA flash attention, fused QKV input [4096][1536]. 512 threads = 8 waves,
// each wave 16 q-rows (QBLK=128). KVBLK=128 staged in LDS (K row-major padded,
// V transposed pair-packed); next chunk prefetched into registers during
// compute. 1/8 scale folded into Q (exact). 256 blocks, XCD-swizzled so each
// (b,h)'s K/V panel stays in one XCD's L2.
// ---------------------------------------------------------------------------
__global__ __launch_bounds__(512) void attn_mfma(const ushort* __restrict__ QKV,
                                                 ushort* __restrict__ CTX) {
    __shared__ ushort Ks[128][72];
    __shared__ ushort VsT[64][136];
    __shared__ ushort Ps[8][16][136];

    int raw = blockIdx.x;
    int bid = (raw & 7) * 32 + (raw >> 3);   // XCD co-locate (grid=256)
    int qt = bid & 15;             // 16 q-tiles of 128 rows
    int hh = (bid >> 4) & 7;
    int bb = bid >> 7;
    int q0 = qt * 128;
    int tid = threadIdx.x;
    int w = tid >> 6, l = tid & 63;
    int c = l & 15, g = l >> 4;

    size_t qbase = (size_t)bb * SS * QS + hh * DHH;
    size_t kbase = qbase + 512;
    size_t vbase = qbase + 1024;
    size_t obase = (size_t)bb * SS * DD + hh * DHH;

    // Q fragments, scaled by 1/8 (exact in bf16)
    short8 qf[2];
    {
        const ushort* qp = QKV + qbase + (size_t)(q0 + w * 16 + c) * QS + g * 8;
        short8 q0v = *(const short8*)qp;
        short8 q1v = *(const short8*)(qp + 32);
#pragma unroll
        for (int j = 0; j < 8; ++j) {
            q0v[j] = (short)f2bf(bf2f((unsigned short)q0v[j]) * 0.125f);
            q1v[j] = (short)f2bf(bf2f((unsigned short)q1v[j]) * 0.125f);
        }
        qf[0] = q0v; qf[1] = q1v;
    }

    // K prefetch: row kk = tid>>2 (0..127), 16 dims at (tid&3)*16
    int kk = tid >> 2, kd0 = (tid & 3) * 16;
    // V prefetch: key pair kp = (tid&63)*2, 8 dims at (tid>>6)*8
    int kp = (tid & 63) * 2, dv = (tid >> 6) * 8;

    short8 kreg[2], vreg[2];
    {
        const short8* gk = (const short8*)(QKV + kbase + (size_t)kk * QS + kd0);
        kreg[0] = gk[0]; kreg[1] = gk[1];
        vreg[0] = *(const short8*)(QKV + vbase + (size_t)kp * QS + dv);
        vreg[1] = *(const short8*)(QKV + vbase + (size_t)(kp + 1) * QS + dv);
    }

    floatx4 O[4] = {};
    float mx[4] = {-1e30f, -1e30f, -1e30f, -1e30f};
    float dn[4] = {};

    for (int ch = 0; ch < SS; ch += 128) {
        __syncthreads();    // prev chunk's readers done; prefetch loads drained
        *(short8*)&Ks[kk][kd0]     = kreg[0];
        *(short8*)&Ks[kk][kd0 + 8] = kreg[1];
#pragma unroll
        for (int j = 0; j < 8; ++j) {
            unsigned int lo = (unsigned short)vreg[0][j], hi = (unsigned short)vreg[1][j];
            *(unsigned int*)&VsT[dv + j][kp] = lo | (hi << 16);
        }
        __syncthreads();    // Ks/VsT ready

        // prefetch next chunk into regs (lands during compute below)
        if (ch + 128 < SS) {
            const short8* gk = (const short8*)(QKV + kbase + (size_t)(ch + 128 + kk) * QS + kd0);
            kreg[0] = gk[0]; kreg[1] = gk[1];
            vreg[0] = *(const short8*)(QKV + vbase + (size_t)(ch + 128 + kp) * QS + dv);
            vreg[1] = *(const short8*)(QKV + vbase + (size_t)(ch + 128 + kp + 1) * QS + dv);
        }

        // QK^T: 16q x 128k per wave (8 key-tiles)
        floatx4 S[8];
        __builtin_amdgcn_s_setprio(1);
#pragma unroll
        for (int t = 0; t < 8; ++t) {
            floatx4 z = {};
            short8 k0 = *(const short8*)&Ks[t * 16 + c][g * 8];
            short8 k1 = *(const short8*)&Ks[t * 16 + c][32 + g * 8];
            mfma16x16x32(z, qf[0], k0);
            mfma16x16x32(z, qf[1], k1);
            S[t] = z;
        }
        __builtin_amdgcn_s_setprio(0);

        // online softmax (scores pre-scaled via Q)
#pragma unroll
        for (int r = 0; r < 4; ++r) {
            float pm = fmaxf(fmaxf(fmaxf(S[0][r], S[1][r]), fmaxf(S[2][r], S[3][r])),
                             fmaxf(fmaxf(S[4][r], S[5][r]), fmaxf(S[6][r], S[7][r])));
            pm = fmaxf(pm, __shfl_xor(pm, 1));
            pm = fmaxf(pm, __shfl_xor(pm, 2));
            pm = fmaxf(pm, __shfl_xor(pm, 4));
            pm = fmaxf(pm, __shfl_xor(pm, 8));
            float nmr = fmaxf(mx[r], pm);
            float scr = __expf(mx[r] - nmr);
            float e[8];
            float ps = 0.f;
#pragma unroll
            for (int t = 0; t < 8; ++t) {
                e[t] = __expf(S[t][r] - nmr);
                ps += e[t];
            }
            ps += __shfl_xor(ps, 1);
            ps += __shfl_xor(ps, 2);
            ps += __shfl_xor(ps, 4);
            ps += __shfl_xor(ps, 8);
            dn[r] = dn[r] * scr + ps;
            mx[r] = nmr;
            O[0][r] *= scr; O[1][r] *= scr; O[2][r] *= scr; O[3][r] *= scr;
            int q = 4 * g + r;
#pragma unroll
            for (int t = 0; t < 8; ++t)
                Ps[w][q][t * 16 + c] = f2bf_fast(e[t]);
        }

        // PV: O += P(16q x 128k) . V(128k x 64d)
        __builtin_amdgcn_s_setprio(1);
#pragma unroll
        for (int s = 0; s < 4; ++s) {
            short8 pa = *(const short8*)&Ps[w][c][s * 32 + g * 8];
#pragma unroll
            for (int dt = 0; dt < 4; ++dt) {
                short8 vb = *(const short8*)&VsT[dt * 16 + c][s * 32 + g * 8];
                mfma16x16x32(O[dt], pa, vb);
            }
        }
        __builtin_amdgcn_s_setprio(0);
    }

    float inv[4];
#pragma unroll
    for (int r = 0; r < 4; ++r) inv[r] = 1.f / dn[r];
#pragma unroll
    for (int dt = 0; dt < 4; ++dt) {
#pragma unroll
        for (int r = 0; r < 4; ++r) {
            size_t op = obase + (size_t)(q0 + w * 16 + 4 * g + r) * DD + dt * 16 + c;
            CTX[op] = f2bf(O[dt][r] * inv[r]);
        }
    }
}

// ---------------------------------------------------------------------------
// hout = LayerNorm(hin + yin [+ y2]) * g + b. 256 threads = 2 rows/block,
// float4 loads, single-pass mean/var. Optional bf16 copy.
// ---------------------------------------------------------------------------
__global__ __launch_bounds__(256) void add_ln(const float* __restrict__ hin,
                                              const float* __restrict__ yin,
                                              const float* __restrict__ y2,
                                              const float* __restrict__ g,
                                              const float* __restrict__ b,
                                              float* __restrict__ hout,
                                              ushort* __restrict__ bout) {
    __shared__ float shs[2][2], shq[2][2];
    int rh = threadIdx.x >> 7;          // row half: 0..1
    int t  = threadIdx.x & 127;         // 0..127
    int wv = (threadIdx.x >> 6) & 1;    // wave within row group
    int row = blockIdx.x * 2 + rh;
    const float4 hv = ((const float4*)(hin + (size_t)row * DD))[t];
    const float4 yv = ((const float4*)(yin + (size_t)row * DD))[t];
    float4 v;
    v.x = hv.x + yv.x; v.y = hv.y + yv.y; v.z = hv.z + yv.z; v.w = hv.w + yv.w;
    if (y2) {
        const float4 y2v = ((const float4*)(y2 + (size_t)row * DD))[t];
        v.x += y2v.x; v.y += y2v.y; v.z += y2v.z; v.w += y2v.w;
    }
    float s = v.x + v.y + v.z + v.w;
    float q = v.x * v.x + v.y * v.y + v.z * v.z + v.w * v.w;
#pragma unroll
    for (int off = 32; off; off >>= 1) {
        s += __shfl_xor(s, off);
        q += __shfl_xor(q, off);
    }
    if ((threadIdx.x & 63) == 0) { shs[rh][wv] = s; shq[rh][wv] = q; }
    __syncthreads();
    float St = shs[rh][0] + shs[rh][1], Qt = shq[rh][0] + shq[rh][1];
    float mean = St * (1.f / 512.f);
    float var = Qt * (1.f / 512.f) - mean * mean;
    float rstd = rsqrtf(var + 1e-5f);
    const float4 gv = ((const float4*)g)[t];
    const float4 bv = ((const float4*)b)[t];
    float4 r;
    r.x = (v.x - mean) * rstd * gv.x + bv.x;
    r.y = (v.y - mean) * rstd * gv.y + bv.y;
    r.z = (v.z - mean) * rstd * gv.z + bv.z;
    r.w = (v.w - mean) * rstd * gv.w + bv.w;
    ((float4*)(hout + (size_t)row * DD))[t] = r;
    if (bout) {
        union { ushort u[4]; unsigned long long ll; } pk;
        pk.u[0] = f2bf(r.x); pk.u[1] = f2bf(r.y);
        pk.u[2] = f2bf(r.z); pk.u[3] = f2bf(r.w);
        *(unsigned long long*)(bout + (size_t)row * DD + t * 4) = pk.ll;
    }
}

// ---------------------------------------------------------------------------
extern "C" void kernel_launch(void* const* d_in, const int* in_sizes, int n_in,
                              void* d_out, int out_size, void* d_ws, size_t ws_size,
                              hipStream_t stream) {
    const int*   x    = (const int*)d_in[0];
    const float* emb  = (const float*)d_in[1];
    const float* Wq   = (const float*)d_in[2];
    const float* bq   = (const float*)d_in[3];
    const float* Wk   = (const float*)d_in[4];
    const float* bk   = (const float*)d_in[5];
    const float* Wv   = (const float*)d_in[6];
    const float* bv   = (const float*)d_in[7];
    const float* Wo   = (const float*)d_in[8];
    const float* bo   = (const float*)d_in[9];
    const float* W1   = (const float*)d_in[10];
    const float* b1   = (const float*)d_in[11];
    const float* W2   = (const float*)d_in[12];
    const float* b2   = (const float*)d_in[13];
    const float* g1   = (const float*)d_in[14];
    const float* be1  = (const float*)d_in[15];
    const float* g2   = (const float*)d_in[16];
    const float* be2  = (const float*)d_in[17];
    float* out = (float*)d_out;

    char* ws = (char*)d_ws;
    size_t off = 0;
    auto alloc = [&](size_t bytes) -> void* {
        void* p = ws + off;
        off += (bytes + 255) & ~(size_t)255;
        return p;
    };
    float*  h    = (float*)alloc((size_t)NROWS * DD * 4);
    float*  y    = (float*)alloc((size_t)NROWS * DD * 4);
    float*  y2   = (float*)alloc((size_t)NROWS * DD * 4);
    ushort* hb   = (ushort*)alloc((size_t)NROWS * DD * 2);
    ushort* qkv  = (ushort*)alloc((size_t)NROWS * QS * 2);   // 12MB
    ushort* ctxb = (ushort*)alloc((size_t)NROWS * DD * 2);   // 4MB (adjacent)
    ushort* ff1  = qkv;   // FF1 [4096][2048] aliases dead qkv+ctxb (16MB)
    ushort* qkvT = (ushort*)alloc((size_t)6 * QS * DD * 2);
    ushort* WoT  = (ushort*)alloc((size_t)6 * DD * DD * 2);
    ushort* W1T  = (ushort*)alloc((size_t)6 * DD * 2048 * 2);
    ushort* W2T  = (ushort*)alloc((size_t)6 * DD * 2048 * 2);
    float*  qkvB = (float*)alloc((size_t)6 * QS * 4);

    if (ws_size < off) return;   // diagnostic guard (zeros signature)

    dim3 tb(32, 8);
    transpose_k<<<dim3(16, 16, 6), tb, 0, stream>>>(Wq, qkvT,              512, 512, QS * DD);
    transpose_k<<<dim3(16, 16, 6), tb, 0, stream>>>(Wk, qkvT + 512 * DD,   512, 512, QS * DD);
    transpose_k<<<dim3(16, 16, 6), tb, 0, stream>>>(Wv, qkvT + 1024 * DD,  512, 512, QS * DD);
    transpose_k<<<dim3(16, 16, 6), tb, 0, stream>>>(Wo, WoT,               512, 512, DD * DD);
    transpose_k<<<dim3(64, 16, 6), tb, 0, stream>>>(W1, W1T,  512, 2048, 2048 * DD);
    transpose_k<<<dim3(16, 64, 6), tb, 0, stream>>>(W2, W2T, 2048,  512, 2048 * DD);
    concat_bias<<<6, 512, 0, stream>>>(bq, bk, bv, qkvB);

    embed_pe<<<NROWS, 256, 0, stream>>>(x, emb, h, hb);

    for (int l = 0; l < 6; ++l) {
        gemm128<<<384, 256, 0, stream>>>(hb, qkvT + (size_t)l * QS * DD, qkvB + l * QS,
                                         nullptr, qkv, nullptr, NROWS, QS, 512, 0, 1);
        attn_mfma<<<256, 512, 0, stream>>>(qkv, ctxb);
        gemm128<<<256, 256, 0, stream>>>(ctxb, WoT + (size_t)l * DD * DD, bo + l * DD,
                                         y, nullptr, y2, NROWS, DD, 512, 0, 2);
        add_ln<<<2048, 256, 0, stream>>>(h, y, y2, g1 + l * DD, be1 + l * DD, h, hb);
        gemm128<<<512, 256, 0, stream>>>(hb, W1T + (size_t)l * 2048 * DD, b1 + l * 2048,
                                         nullptr, ff1, nullptr, NROWS, 2048, 512, 1, 1);
        gemm128<<<256, 256, 0, stream>>>(ff1, W2T + (size_t)l * 2048 * DD, b2 + l * DD,
                                         y, nullptr, y2, NROWS, DD, 2048, 0, 2);
        add_ln<<<2048, 256, 0, stream>>>(h, y, y2, g2 + l * DD, be2 + l * DD,
                                         (l == 5) ? out : h, (l == 5) ? nullptr : hb);
    }
}

// Round 8
// 816.540 us; speedup vs baseline: 8.0868x; 1.0927x over previous
//
#include <hip/hip_runtime.h>
#include <hip/hip_bf16.h>

// ---------------------------------------------------------------------------
// TransformerEncoder: B=2, S=2048, D=512, H=8, DH=64, DF=2048, NX=6 layers
// I/O fp32. bf16 MFMA GEMMs (128-tile, BK=64, XOR-swizzled LDS reads with
// pre-swizzled global_load_lds source, 2-phase dbuf, XCD swizzle, split-K),
// fused QKV, 8-wave MFMA flash attention (QBLK=128, defer-max), fp32 LN.
// ---------------------------------------------------------------------------

typedef __attribute__((ext_vector_type(4))) float  floatx4;
typedef __attribute__((ext_vector_type(8))) short  short8;
typedef __bf16 bf16x8 __attribute__((ext_vector_type(8)));

#define SS 2048
#define DD 512
#define HH 8
#define DHH 64
#define NROWS 4096   /* B*S */
#define QS 1536      /* fused qkv row stride */

__device__ __forceinline__ float bf2f(unsigned short u) {
    union { float f; unsigned int i; } x; x.i = ((unsigned int)u) << 16; return x.f;
}
__device__ __forceinline__ unsigned short f2bf(float f) {
    union { float f; unsigned int i; } x; x.f = f;
    unsigned int lsb = (x.i >> 16) & 1u;
    x.i += 0x7fffu + lsb;
    return (unsigned short)(x.i >> 16);
}
// round-half-up for positive finite values (softmax P)
__device__ __forceinline__ unsigned short f2bf_fast(float f) {
    union { float f; unsigned int i; } x; x.f = f;
    return (unsigned short)((x.i + 0x8000u) >> 16);
}

#if __has_builtin(__builtin_amdgcn_mfma_f32_16x16x32_bf16)
__device__ __forceinline__ void mfma16x16x32(floatx4& d, short8 a, short8 b) {
    bf16x8 ab, bb;
    __builtin_memcpy(&ab, &a, 16);
    __builtin_memcpy(&bb, &b, 16);
    d = __builtin_amdgcn_mfma_f32_16x16x32_bf16(ab, bb, d, 0, 0, 0);
}
#else
__device__ __forceinline__ void mfma16x16x32(floatx4& d, short8 a, short8 b) {
    asm volatile("s_nop 1\n\t"
                 "v_mfma_f32_16x16x32_bf16 %0, %1, %2, %0\n\t"
                 "s_nop 7\n\t"
                 "s_nop 7"
                 : "+v"(d) : "v"(a), "v"(b));
}
#endif

// stage 16B/lane: g = per-lane global src, lbase = wave-uniform LDS chunk base
#if __has_builtin(__builtin_amdgcn_global_load_lds)
__device__ __forceinline__ void stage16(const ushort* g, ushort* lbase, int lane) {
    __builtin_amdgcn_global_load_lds(
        (const __attribute__((address_space(1))) unsigned int*)g,
        (__attribute__((address_space(3))) unsigned int*)lbase, 16, 0, 0);
}
#else
__device__ __forceinline__ void stage16(const ushort* g, ushort* lbase, int lane) {
    *(short8*)(lbase + lane * 8) = *(const short8*)g;
}
#endif

// ---------------------------------------------------------------------------
// Weight transpose + fp32->bf16: W [z][R][C] fp32 -> dst [z*zstride + C*R] bf16
// ---------------------------------------------------------------------------
__global__ __launch_bounds__(256) void transpose_k(const float* __restrict__ W,
                                                   ushort* __restrict__ WT,
                                                   int R, int C, int zstride) {
    __shared__ ushort t[32][33];
    int z = blockIdx.z;
    const float* Wz = W + (size_t)z * R * C;
    ushort* WTz = WT + (size_t)z * zstride;
    int c0 = blockIdx.x * 32, r0 = blockIdx.y * 32;
    int x = threadIdx.x, y = threadIdx.y;         // (32,8)
#pragma unroll
    for (int i = 0; i < 32; i += 8)
        t[y + i][x] = f2bf(Wz[(size_t)(r0 + y + i) * C + c0 + x]);
    __syncthreads();
#pragma unroll
    for (int i = 0; i < 32; i += 8)
        WTz[(size_t)(c0 + y + i) * R + r0 + x] = t[x][y + i];
}

__global__ __launch_bounds__(512) void concat_bias(const float* __restrict__ bq,
                                                   const float* __restrict__ bk,
                                                   const float* __restrict__ bv,
                                                   float* __restrict__ qkvB) {
    int l = blockIdx.x, t = threadIdx.x;
    qkvB[l * QS + t]        = bq[l * DD + t];
    qkvB[l * QS + 512 + t]  = bk[l * DD + t];
    qkvB[l * QS + 1024 + t] = bv[l * DD + t];
}

// ---------------------------------------------------------------------------
// Embedding + positional encoding.
// ---------------------------------------------------------------------------
__global__ __launch_bounds__(256) void embed_pe(const int* __restrict__ x,
                                                const float* __restrict__ emb,
                                                float* __restrict__ h,
                                                ushort* __restrict__ hb) {
    __shared__ int isI32;
    int row = blockIdx.x, tid = threadIdx.x;
    if (tid == 0) isI32 = 0;
    __syncthreads();
    int acc = 0;
    for (int i = tid; i < 2048; i += 256) acc |= x[2 * i + 1];
    if (acc) isI32 = 1;
    __syncthreads();
    int tok = isI32 ? x[row] : x[2 * row];
    int s = row & (SS - 1);
    const float* er = emb + (size_t)tok * DD;
    for (int c = tid; c < DD; c += 256) {
        float e = er[c] * 22.62741699796952f;              // sqrt(512)
        float freq = __expf(-((float)c * (1.f / 256.f)) * 9.210340371976184f);
        float ang = (float)s * freq;
        float pe = (c & 1) ? cosf(ang) : sinf(ang);
        float val = e + pe;
        h[(size_t)row * DD + c] = val;
        hb[(size_t)row * DD + c] = f2bf(val);
    }
}

// ---------------------------------------------------------------------------
// 2-phase pipelined GEMM. BM=BN=128, BK=64, double-buffered LDS (64KB), one
// barrier per K-step. LDS rows are 128B: linear layout would be a 16-way
// ds_read conflict, so the global source column is pre-swizzled per lane
// (group ^= row&7) and ds_reads XOR the same pattern (rule #21: both sides).
// XCD-bijective swizzle (grid%8==0). Optional split-K (ks=0: bias -> Cf/Cb;
// ks=1: raw partial -> Cf2).
// ---------------------------------------------------------------------------
__global__ __launch_bounds__(256) void gemm128(const ushort* __restrict__ A,
                                               const ushort* __restrict__ BT,
                                               const float* __restrict__ bias,
                                               float* __restrict__ Cf,
                                               ushort* __restrict__ Cb,
                                               float* __restrict__ Cf2,
                                               int M, int N, int K,
                                               int relu, int splitk) {
    constexpr int MI = 4, NI = 4;
    __shared__ ushort As[2][128 * 64];
    __shared__ ushort Bs[2][128 * 64];

    int nwg = gridDim.x;
    int raw = blockIdx.x;
    int bs = (raw & 7) * (nwg >> 3) + (raw >> 3);   // XCD co-locate
    int kblocks = nwg / splitk;
    int ks = bs / kblocks;
    int tb = bs - ks * kblocks;
    int Keff = K / splitk;
    int kofs = ks * Keff;

    int nbn = N >> 7;
    int bm = (tb / nbn) << 7;
    int bn = (tb % nbn) << 7;
    int tid = threadIdx.x;
    int lane = tid & 63, w = tid >> 6;
    int lr = lane & 15, lg = lane >> 4;

    // staging: chunk = 8 rows x 64 cols = 1KB; lane -> row=lane>>3 within
    // chunk; global col group pre-swizzled by row&7 so LDS slot s holds
    // global group s^(row&7).
    int srow = lane >> 3;
    int scol = ((lane & 7) ^ srow) * 8;
    const ushort* gA = A + (size_t)(bm + w * 32 + srow) * K + kofs + scol;
    const ushort* gB = BT + (size_t)(bn + w * 32 + srow) * K + kofs + scol;
    const size_t chG = (size_t)8 * K;     // global row-block step per chunk

    int wr = (w >> 1) * 64;
    int wc = (w & 1) * 64;

    // swizzled ds_read offsets (ushort units): row*64 + ((kh*32+lg*8) ^ ((row&7)*8))
    int arow[MI], brow[NI];
#pragma unroll
    for (int mi = 0; mi < MI; ++mi) arow[mi] = wr + mi * 16 + lr;
#pragma unroll
    for (int ni = 0; ni < NI; ++ni) brow[ni] = wc + ni * 16 + lr;

    floatx4 acc[MI][NI] = {};
    int T = Keff >> 6;

    // prologue: stage tile 0 into buffer 0 (4 chunks each of A,B per wave)
#pragma unroll
    for (int ch = 0; ch < 4; ++ch) {
        stage16(gA + ch * chG, &As[0][(w * 32 + ch * 8) * 64], lane);
        stage16(gB + ch * chG, &Bs[0][(w * 32 + ch * 8) * 64], lane);
    }
    __syncthreads();

    for (int t = 0; t < T; ++t) {
        int cur = t & 1;
        if (t + 1 < T) {               // issue next-tile loads (overlap compute)
            int ko = (t + 1) * 64;
#pragma unroll
            for (int ch = 0; ch < 4; ++ch) {
                stage16(gA + ch * chG + ko, &As[cur ^ 1][(w * 32 + ch * 8) * 64], lane);
                stage16(gB + ch * chG + ko, &Bs[cur ^ 1][(w * 32 + ch * 8) * 64], lane);
            }
        }
        short8 af[MI][2], bf[NI][2];
#pragma unroll
        for (int mi = 0; mi < MI; ++mi) {
            int r = arow[mi], sw = (r & 7) * 8;
            af[mi][0] = *(const short8*)&As[cur][r * 64 + ((lg * 8) ^ sw)];
            af[mi][1] = *(const short8*)&As[cur][r * 64 + ((32 + lg * 8) ^ sw)];
        }
#pragma unroll
        for (int ni = 0; ni < NI; ++ni) {
            int r = brow[ni], sw = (r & 7) * 8;
            bf[ni][0] = *(const short8*)&Bs[cur][r * 64 + ((lg * 8) ^ sw)];
            bf[ni][1] = *(const short8*)&Bs[cur][r * 64 + ((32 + lg * 8) ^ sw)];
        }
#pragma unroll
        for (int kh = 0; kh < 2; ++kh)
#pragma unroll
            for (int mi = 0; mi < MI; ++mi)
#pragma unroll
                for (int ni = 0; ni < NI; ++ni)
                    mfma16x16x32(acc[mi][ni], af[mi][kh], bf[ni][kh]);
        if (t + 1 < T) __syncthreads();
    }

#pragma unroll
    for (int ni = 0; ni < NI; ++ni) {
        int col = bn + wc + ni * 16 + lr;
        float bv = ks ? 0.f : bias[col];
#pragma unroll
        for (int mi = 0; mi < MI; ++mi) {
#pragma unroll
            for (int rr = 0; rr < 4; ++rr) {
                int rowi = bm + wr + mi * 16 + lg * 4 + rr;
                float v = acc[mi][ni][rr] + bv;
                if (relu) v = fmaxf(v, 0.f);
                size_t idx = (size_t)rowi * N + col;
                if (ks) { Cf2[idx] = v; }
                else {
                    if (Cf) Cf[idx] = v;
                    if (Cb) Cb[idx] = f2bf(v);
                }
            }
        }
    }
}

// ---------------------------------------------------------------------------
// MFMA flash attention, fused QKV input [4096][1536]. 512 threads = 8 waves,
// each wave 16 q-rows (QBLK=128). KVBLK=128 staged in LDS (K row-major padded,
// V transposed pair-packed); next chunk reg-prefetched during compute.
// Defer-max (THR=8): skip max-shuffles + O-rescale while per-tile max stays
// within 8 of the running max (P bounded by e^8; fp32/bf16 headroom fine).
// ---------------------------------------------------------------------------
__global__ __launch_bounds__(512) void attn_mfma(const ushort* __restrict__ QKV,
                                                 ushort* __restrict__ CTX) {
    __shared__ ushort Ks[128][72];
    __shared__ ushort VsT[64][136];
    __shared__ ushort Ps[8][16][136];

    int raw = blockIdx.x;
    int bid = (raw & 7) * 32 + (raw >> 3);   // XCD co-locate (grid=256)
    int qt = bid & 15;             // 16 q-tiles of 128 rows
    int hh = (bid >> 4) & 7;
    int bb = bid >> 7;
    int q0 = qt * 128;
    int tid = threadIdx.x;
    int w = tid >> 6, l = tid & 63;
    int c = l & 15, g = l >> 4;

    size_t qbase = (size_t)bb * SS * QS + hh * DHH;
    size_t kbase = qbase + 512;
    size_t vbase = qbase + 1024;
    size_t obase = (size_t)bb * SS * DD + hh * DHH;

    // Q fragments, scaled by 1/8 (exact in bf16)
    short8 qf[2];
    {
        const ushort* qp = QKV + qbase + (size_t)(q0 + w * 16 + c) * QS + g * 8;
        short8 q0v = *(const short8*)qp;
        short8 q1v = *(const short8*)(qp + 32);
#pragma unroll
        for (int j = 0; j < 8; ++j) {
            q0v[j] = (short)f2bf(bf2f((unsigned short)q0v[j]) * 0.125f);
            q1v[j] = (short)f2bf(bf2f((unsigned short)q1v[j]) * 0.125f);
        }
        qf[0] = q0v; qf[1] = q1v;
    }

    // K prefetch: row kk = tid>>2 (0..127), 16 dims at (tid&3)*16
    int kk = tid >> 2, kd0 = (tid & 3) * 16;
    // V prefetch: key pair kp = (tid&63)*2, 8 dims at (tid>>6)*8
    int kp = (tid & 63) * 2, dv = (tid >> 6) * 8;

    short8 kreg[2], vreg[2];
    {
        const short8* gk = (const short8*)(QKV + kbase + (size_t)kk * QS + kd0);
        kreg[0] = gk[0]; kreg[1] = gk[1];
        vreg[0] = *(const short8*)(QKV + vbase + (size_t)kp * QS + dv);
        vreg[1] = *(const short8*)(QKV + vbase + (size_t)(kp + 1) * QS + dv);
    }

    floatx4 O[4] = {};
    float mx[4] = {-1e30f, -1e30f, -1e30f, -1e30f};
    float dn[4] = {};

    for (int ch = 0; ch < SS; ch += 128) {
        __syncthreads();    // prev chunk's readers done; prefetch loads drained
        *(short8*)&Ks[kk][kd0]     = kreg[0];
        *(short8*)&Ks[kk][kd0 + 8] = kreg[1];
#pragma unroll
        for (int j = 0; j < 8; ++j) {
            unsigned int lo = (unsigned short)vreg[0][j], hi = (unsigned short)vreg[1][j];
            *(unsigned int*)&VsT[dv + j][kp] = lo | (hi << 16);
        }
        __syncthreads();    // Ks/VsT ready

        // prefetch next chunk into regs (lands during compute below)
        if (ch + 128 < SS) {
            const short8* gk = (const short8*)(QKV + kbase + (size_t)(ch + 128 + kk) * QS + kd0);
            kreg[0] = gk[0]; kreg[1] = gk[1];
            vreg[0] = *(const short8*)(QKV + vbase + (size_t)(ch + 128 + kp) * QS + dv);
            vreg[1] = *(const short8*)(QKV + vbase + (size_t)(ch + 128 + kp + 1) * QS + dv);
        }

        // QK^T: 16q x 128k per wave (8 key-tiles)
        floatx4 S[8];
        __builtin_amdgcn_s_setprio(1);
#pragma unroll
        for (int t = 0; t < 8; ++t) {
            floatx4 z = {};
            short8 k0 = *(const short8*)&Ks[t * 16 + c][g * 8];
            short8 k1 = *(const short8*)&Ks[t * 16 + c][32 + g * 8];
            mfma16x16x32(z, qf[0], k0);
            mfma16x16x32(z, qf[1], k1);
            S[t] = z;
        }
        __builtin_amdgcn_s_setprio(0);

        // online softmax with defer-max (scores pre-scaled via Q)
#pragma unroll
        for (int r = 0; r < 4; ++r) {
            float pml = fmaxf(fmaxf(fmaxf(S[0][r], S[1][r]), fmaxf(S[2][r], S[3][r])),
                              fmaxf(fmaxf(S[4][r], S[5][r]), fmaxf(S[6][r], S[7][r])));
            if (!__all(pml - mx[r] <= 8.f)) {
                float pm = pml;
                pm = fmaxf(pm, __shfl_xor(pm, 1));
                pm = fmaxf(pm, __shfl_xor(pm, 2));
                pm = fmaxf(pm, __shfl_xor(pm, 4));
                pm = fmaxf(pm, __shfl_xor(pm, 8));
                float nmr = fmaxf(mx[r], pm);
                float scr = __expf(mx[r] - nmr);
                dn[r] *= scr;
                O[0][r] *= scr; O[1][r] *= scr; O[2][r] *= scr; O[3][r] *= scr;
                mx[r] = nmr;
            }
            float e[8];
            float ps = 0.f;
#pragma unroll
            for (int t = 0; t < 8; ++t) {
                e[t] = __expf(S[t][r] - mx[r]);
                ps += e[t];
            }
            ps += __shfl_xor(ps, 1);
            ps += __shfl_xor(ps, 2);
            ps += __shfl_xor(ps, 4);
            ps += __shfl_xor(ps, 8);
            dn[r] += ps;
            int q = 4 * g + r;
#pragma unroll
            for (int t = 0; t < 8; ++t)
                Ps[w][q][t * 16 + c] = f2bf_fast(e[t]);
        }

        // PV: O += P(16q x 128k) . V(128k x 64d)
        __builtin_amdgcn_s_setprio(1);
#pragma unroll
        for (int s = 0; s < 4; ++s) {
            short8 pa = *(const short8*)&Ps[w][c][s * 32 + g * 8];
#pragma unroll
            for (int dt = 0; dt < 4; ++dt) {
                short8 vb = *(const short8*)&VsT[dt * 16 + c][s * 32 + g * 8];
                mfma16x16x32(O[dt], pa, vb);
            }
        }
        __builtin_amdgcn_s_setprio(0);
    }

    float inv[4];
#pragma unroll
    for (int r = 0; r < 4; ++r) inv[r] = 1.f / dn[r];
#pragma unroll
    for (int dt = 0; dt < 4; ++dt) {
#pragma unroll
        for (int r = 0; r < 4; ++r) {
            size_t op = obase + (size_t)(q0 + w * 16 + 4 * g + r) * DD + dt * 16 + c;
            CTX[op] = f2bf(O[dt][r] * inv[r]);
        }
    }
}

// ---------------------------------------------------------------------------
// hout = LayerNorm(hin + yin [+ y2]) * g + b. 256 threads = 2 rows/block,
// float4 loads, single-pass mean/var. Optional bf16 copy.
// ---------------------------------------------------------------------------
__global__ __launch_bounds__(256) void add_ln(const float* __restrict__ hin,
                                              const float* __restrict__ yin,
                                              const float* __restrict__ y2,
                                              const float* __restrict__ g,
                                              const float* __restrict__ b,
                                              float* __restrict__ hout,
                                              ushort* __restrict__ bout) {
    __shared__ float shs[2][2], shq[2][2];
    int rh = threadIdx.x >> 7;          // row half: 0..1
    int t  = threadIdx.x & 127;         // 0..127
    int wv = (threadIdx.x >> 6) & 1;    // wave within row group
    int row = blockIdx.x * 2 + rh;
    const float4 hv = ((const float4*)(hin + (size_t)row * DD))[t];
    const float4 yv = ((const float4*)(yin + (size_t)row * DD))[t];
    float4 v;
    v.x = hv.x + yv.x; v.y = hv.y + yv.y; v.z = hv.z + yv.z; v.w = hv.w + yv.w;
    if (y2) {
        const float4 y2v = ((const float4*)(y2 + (size_t)row * DD))[t];
        v.x += y2v.x; v.y += y2v.y; v.z += y2v.z; v.w += y2v.w;
    }
    float s = v.x + v.y + v.z + v.w;
    float q = v.x * v.x + v.y * v.y + v.z * v.z + v.w * v.w;
#pragma unroll
    for (int off = 32; off; off >>= 1) {
        s += __shfl_xor(s, off);
        q += __shfl_xor(q, off);
    }
    if ((threadIdx.x & 63) == 0) { shs[rh][wv] = s; shq[rh][wv] = q; }
    __syncthreads();
    float St = shs[rh][0] + shs[rh][1], Qt = shq[rh][0] + shq[rh][1];
    float mean = St * (1.f / 512.f);
    float var = Qt * (1.f / 512.f) - mean * mean;
    float rstd = rsqrtf(var + 1e-5f);
    const float4 gv = ((const float4*)g)[t];
    const float4 bv = ((const float4*)b)[t];
    float4 r;
    r.x = (v.x - mean) * rstd * gv.x + bv.x;
    r.y = (v.y - mean) * rstd * gv.y + bv.y;
    r.z = (v.z - mean) * rstd * gv.z + bv.z;
    r.w = (v.w - mean) * rstd * gv.w + bv.w;
    ((float4*)(hout + (size_t)row * DD))[t] = r;
    if (bout) {
        union { ushort u[4]; unsigned long long ll; } pk;
        pk.u[0] = f2bf(r.x); pk.u[1] = f2bf(r.y);
        pk.u[2] = f2bf(r.z); pk.u[3] = f2bf(r.w);
        *(unsigned long long*)(bout + (size_t)row * DD + t * 4) = pk.ll;
    }
}

// ---------------------------------------------------------------------------
extern "C" void kernel_launch(void* const* d_in, const int* in_sizes, int n_in,
                              void* d_out, int out_size, void* d_ws, size_t ws_size,
                              hipStream_t stream) {
    const int*   x    = (const int*)d_in[0];
    const float* emb  = (const float*)d_in[1];
    const float* Wq   = (const float*)d_in[2];
    const float* bq   = (const float*)d_in[3];
    const float* Wk   = (const float*)d_in[4];
    const float* bk   = (const float*)d_in[5];
    const float* Wv   = (const float*)d_in[6];
    const float* bv   = (const float*)d_in[7];
    const float* Wo   = (const float*)d_in[8];
    const float* bo   = (const float*)d_in[9];
    const float* W1   = (const float*)d_in[10];
    const float* b1   = (const float*)d_in[11];
    const float* W2   = (const float*)d_in[12];
    const float* b2   = (const float*)d_in[13];
    const float* g1   = (const float*)d_in[14];
    const float* be1  = (const float*)d_in[15];
    const float* g2   = (const float*)d_in[16];
    const float* be2  = (const float*)d_in[17];
    float* out = (float*)d_out;

    char* ws = (char*)d_ws;
    size_t off = 0;
    auto alloc = [&](size_t bytes) -> void* {
        void* p = ws + off;
        off += (bytes + 255) & ~(size_t)255;
        return p;
    };
    float*  h    = (float*)alloc((size_t)NROWS * DD * 4);
    float*  y    = (float*)alloc((size_t)NROWS * DD * 4);
    float*  y2   = (float*)alloc((size_t)NROWS * DD * 4);
    ushort* hb   = (ushort*)alloc((size_t)NROWS * DD * 2);
    ushort* qkv  = (ushort*)alloc((size_t)NROWS * QS * 2);   // 12MB
    ushort* ctxb = (ushort*)alloc((size_t)NROWS * DD * 2);   // 4MB (adjacent)
    ushort* ff1  = qkv;   // FF1 [4096][2048] aliases dead qkv+ctxb (16MB)
    ushort* qkvT = (ushort*)alloc((size_t)6 * QS * DD * 2);
    ushort* WoT  = (ushort*)alloc((size_t)6 * DD * DD * 2);
    ushort* W1T  = (ushort*)alloc((size_t)6 * DD * 2048 * 2);
    ushort* W2T  = (ushort*)alloc((size_t)6 * DD * 2048 * 2);
    float*  qkvB = (float*)alloc((size_t)6 * QS * 4);

    if (ws_size < off) return;   // diagnostic guard (zeros signature)

    dim3 tb(32, 8);
    transpose_k<<<dim3(16, 16, 6), tb, 0, stream>>>(Wq, qkvT,              512, 512, QS * DD);
    transpose_k<<<dim3(16, 16, 6), tb, 0, stream>>>(Wk, qkvT + 512 * DD,   512, 512, QS * DD);
    transpose_k<<<dim3(16, 16, 6), tb, 0, stream>>>(Wv, qkvT + 1024 * DD,  512, 512, QS * DD);
    transpose_k<<<dim3(16, 16, 6), tb, 0, stream>>>(Wo, WoT,               512, 512, DD * DD);
    transpose_k<<<dim3(64, 16, 6), tb, 0, stream>>>(W1, W1T,  512, 2048, 2048 * DD);
    transpose_k<<<dim3(16, 64, 6), tb, 0, stream>>>(W2, W2T, 2048,  512, 2048 * DD);
    concat_bias<<<6, 512, 0, stream>>>(bq, bk, bv, qkvB);

    embed_pe<<<NROWS, 256, 0, stream>>>(x, emb, h, hb);

    for (int l = 0; l < 6; ++l) {
        gemm128<<<384, 256, 0, stream>>>(hb, qkvT + (size_t)l * QS * DD, qkvB + l * QS,
                                         nullptr, qkv, nullptr, NROWS, QS, 512, 0, 1);
        attn_mfma<<<256, 512, 0, stream>>>(qkv, ctxb);
        gemm128<<<256, 256, 0, stream>>>(ctxb, WoT + (size_t)l * DD * DD, bo + l * DD,
                                         y, nullptr, y2, NROWS, DD, 512, 0, 2);
        add_ln<<<2048, 256, 0, stream>>>(h, y, y2, g1 + l * DD, be1 + l * DD, h, hb);
        gemm128<<<512, 256, 0, stream>>>(hb, W1T + (size_t)l * 2048 * DD, b1 + l * 2048,
                                         nullptr, ff1, nullptr, NROWS, 2048, 512, 1, 1);
        gemm128<<<256, 256, 0, stream>>>(ff1, W2T + (size_t)l * 2048 * DD, b2 + l * DD,
                                         y, nullptr, y2, NROWS, DD, 2048, 0, 2);
        add_ln<<<2048, 256, 0, stream>>>(h, y, y2, g2 + l * DD, be2 + l * DD,
                                         (l == 5) ? out : h, (l == 5) ? nullptr : hb);
    }
}

// Round 9
// 787.913 us; speedup vs baseline: 8.3807x; 1.0363x over previous
//
#include <hip/hip_runtime.h>
#include <hip/hip_bf16.h>

// ---------------------------------------------------------------------------
// TransformerEncoder: B=2, S=2048, D=512, H=8, DH=64, DF=2048, NX=6 layers
// I/O fp32. bf16 MFMA GEMMs (128-tile, BK=64, XOR-swizzled LDS reads with
// pre-swizzled global_load_lds source, 2-phase dbuf, XCD swizzle, split-K),
// fused QKV, 8-wave MFMA flash attention (QBLK=128, defer-max, exp2-domain
// softmax, per-lane denominator), fp32 LN.
// ---------------------------------------------------------------------------

typedef __attribute__((ext_vector_type(4))) float  floatx4;
typedef __attribute__((ext_vector_type(8))) short  short8;
typedef __bf16 bf16x8 __attribute__((ext_vector_type(8)));

#define SS 2048
#define DD 512
#define HH 8
#define DHH 64
#define NROWS 4096   /* B*S */
#define QS 1536      /* fused qkv row stride */

__device__ __forceinline__ float bf2f(unsigned short u) {
    union { float f; unsigned int i; } x; x.i = ((unsigned int)u) << 16; return x.f;
}
__device__ __forceinline__ unsigned short f2bf(float f) {
    union { float f; unsigned int i; } x; x.f = f;
    unsigned int lsb = (x.i >> 16) & 1u;
    x.i += 0x7fffu + lsb;
    return (unsigned short)(x.i >> 16);
}
// round-half-up for positive finite values (softmax P)
__device__ __forceinline__ unsigned short f2bf_fast(float f) {
    union { float f; unsigned int i; } x; x.f = f;
    return (unsigned short)((x.i + 0x8000u) >> 16);
}

#if __has_builtin(__builtin_amdgcn_exp2f)
#define EXP2F(x) __builtin_amdgcn_exp2f(x)
#else
#define EXP2F(x) exp2f(x)
#endif

#if __has_builtin(__builtin_amdgcn_mfma_f32_16x16x32_bf16)
__device__ __forceinline__ void mfma16x16x32(floatx4& d, short8 a, short8 b) {
    bf16x8 ab, bb;
    __builtin_memcpy(&ab, &a, 16);
    __builtin_memcpy(&bb, &b, 16);
    d = __builtin_amdgcn_mfma_f32_16x16x32_bf16(ab, bb, d, 0, 0, 0);
}
#else
__device__ __forceinline__ void mfma16x16x32(floatx4& d, short8 a, short8 b) {
    asm volatile("s_nop 1\n\t"
                 "v_mfma_f32_16x16x32_bf16 %0, %1, %2, %0\n\t"
                 "s_nop 7\n\t"
                 "s_nop 7"
                 : "+v"(d) : "v"(a), "v"(b));
}
#endif

// stage 16B/lane: g = per-lane global src, lbase = wave-uniform LDS chunk base
#if __has_builtin(__builtin_amdgcn_global_load_lds)
__device__ __forceinline__ void stage16(const ushort* g, ushort* lbase, int lane) {
    __builtin_amdgcn_global_load_lds(
        (const __attribute__((address_space(1))) unsigned int*)g,
        (__attribute__((address_space(3))) unsigned int*)lbase, 16, 0, 0);
}
#else
__device__ __forceinline__ void stage16(const ushort* g, ushort* lbase, int lane) {
    *(short8*)(lbase + lane * 8) = *(const short8*)g;
}
#endif

// ---------------------------------------------------------------------------
// Weight transpose + fp32->bf16: W [z][R][C] fp32 -> dst [z*zstride + C*R] bf16
// ---------------------------------------------------------------------------
__global__ __launch_bounds__(256) void transpose_k(const float* __restrict__ W,
                                                   ushort* __restrict__ WT,
                                                   int R, int C, int zstride) {
    __shared__ ushort t[32][33];
    int z = blockIdx.z;
    const float* Wz = W + (size_t)z * R * C;
    ushort* WTz = WT + (size_t)z * zstride;
    int c0 = blockIdx.x * 32, r0 = blockIdx.y * 32;
    int x = threadIdx.x, y = threadIdx.y;         // (32,8)
#pragma unroll
    for (int i = 0; i < 32; i += 8)
        t[y + i][x] = f2bf(Wz[(size_t)(r0 + y + i) * C + c0 + x]);
    __syncthreads();
#pragma unroll
    for (int i = 0; i < 32; i += 8)
        WTz[(size_t)(c0 + y + i) * R + r0 + x] = t[x][y + i];
}

__global__ __launch_bounds__(512) void concat_bias(const float* __restrict__ bq,
                                                   const float* __restrict__ bk,
                                                   const float* __restrict__ bv,
                                                   float* __restrict__ qkvB) {
    int l = blockIdx.x, t = threadIdx.x;
    qkvB[l * QS + t]        = bq[l * DD + t];
    qkvB[l * QS + 512 + t]  = bk[l * DD + t];
    qkvB[l * QS + 1024 + t] = bv[l * DD + t];
}

// ---------------------------------------------------------------------------
// Embedding + positional encoding.
// ---------------------------------------------------------------------------
__global__ __launch_bounds__(256) void embed_pe(const int* __restrict__ x,
                                                const float* __restrict__ emb,
                                                float* __restrict__ h,
                                                ushort* __restrict__ hb) {
    __shared__ int isI32;
    int row = blockIdx.x, tid = threadIdx.x;
    if (tid == 0) isI32 = 0;
    __syncthreads();
    int acc = 0;
    for (int i = tid; i < 2048; i += 256) acc |= x[2 * i + 1];
    if (acc) isI32 = 1;
    __syncthreads();
    int tok = isI32 ? x[row] : x[2 * row];
    int s = row & (SS - 1);
    const float* er = emb + (size_t)tok * DD;
    for (int c = tid; c < DD; c += 256) {
        float e = er[c] * 22.62741699796952f;              // sqrt(512)
        float freq = __expf(-((float)c * (1.f / 256.f)) * 9.210340371976184f);
        float ang = (float)s * freq;
        float pe = (c & 1) ? cosf(ang) : sinf(ang);
        float val = e + pe;
        h[(size_t)row * DD + c] = val;
        hb[(size_t)row * DD + c] = f2bf(val);
    }
}

// ---------------------------------------------------------------------------
// 2-phase pipelined GEMM. BM=BN=128, BK=64, double-buffered LDS (64KB), one
// barrier per K-step. LDS rows are 128B: linear layout would be a 16-way
// ds_read conflict, so the global source column is pre-swizzled per lane
// (group ^= row&7) and ds_reads XOR the same pattern (rule #21: both sides).
// XCD-bijective swizzle (grid%8==0). Optional split-K (ks=0: bias -> Cf/Cb;
// ks=1: raw partial -> Cf2).
// ---------------------------------------------------------------------------
__global__ __launch_bounds__(256) void gemm128(const ushort* __restrict__ A,
                                               const ushort* __restrict__ BT,
                                               const float* __restrict__ bias,
                                               float* __restrict__ Cf,
                                               ushort* __restrict__ Cb,
                                               float* __restrict__ Cf2,
                                               int M, int N, int K,
                                               int relu, int splitk) {
    constexpr int MI = 4, NI = 4;
    __shared__ ushort As[2][128 * 64];
    __shared__ ushort Bs[2][128 * 64];

    int nwg = gridDim.x;
    int raw = blockIdx.x;
    int bs = (raw & 7) * (nwg >> 3) + (raw >> 3);   // XCD co-locate
    int kblocks = nwg / splitk;
    int ks = bs / kblocks;
    int tb = bs - ks * kblocks;
    int Keff = K / splitk;
    int kofs = ks * Keff;

    int nbn = N >> 7;
    int bm = (tb / nbn) << 7;
    int bn = (tb % nbn) << 7;
    int tid = threadIdx.x;
    int lane = tid & 63, w = tid >> 6;
    int lr = lane & 15, lg = lane >> 4;

    // staging: chunk = 8 rows x 64 cols = 1KB; lane -> row=lane>>3 within
    // chunk; global col group pre-swizzled by row&7 so LDS slot s holds
    // global group s^(row&7).
    int srow = lane >> 3;
    int scol = ((lane & 7) ^ srow) * 8;
    const ushort* gA = A + (size_t)(bm + w * 32 + srow) * K + kofs + scol;
    const ushort* gB = BT + (size_t)(bn + w * 32 + srow) * K + kofs + scol;
    const size_t chG = (size_t)8 * K;     // global row-block step per chunk

    int wr = (w >> 1) * 64;
    int wc = (w & 1) * 64;

    // swizzled ds_read offsets (ushort units): row*64 + ((kh*32+lg*8) ^ ((row&7)*8))
    int arow[MI], brow[NI];
#pragma unroll
    for (int mi = 0; mi < MI; ++mi) arow[mi] = wr + mi * 16 + lr;
#pragma unroll
    for (int ni = 0; ni < NI; ++ni) brow[ni] = wc + ni * 16 + lr;

    floatx4 acc[MI][NI] = {};
    int T = Keff >> 6;

    // prologue: stage tile 0 into buffer 0 (4 chunks each of A,B per wave)
#pragma unroll
    for (int ch = 0; ch < 4; ++ch) {
        stage16(gA + ch * chG, &As[0][(w * 32 + ch * 8) * 64], lane);
        stage16(gB + ch * chG, &Bs[0][(w * 32 + ch * 8) * 64], lane);
    }
    __syncthreads();

    for (int t = 0; t < T; ++t) {
        int cur = t & 1;
        if (t + 1 < T) {               // issue next-tile loads (overlap compute)
            int ko = (t + 1) * 64;
#pragma unroll
            for (int ch = 0; ch < 4; ++ch) {
                stage16(gA + ch * chG + ko, &As[cur ^ 1][(w * 32 + ch * 8) * 64], lane);
                stage16(gB + ch * chG + ko, &Bs[cur ^ 1][(w * 32 + ch * 8) * 64], lane);
            }
        }
        short8 af[MI][2], bf[NI][2];
#pragma unroll
        for (int mi = 0; mi < MI; ++mi) {
            int r = arow[mi], sw = (r & 7) * 8;
            af[mi][0] = *(const short8*)&As[cur][r * 64 + ((lg * 8) ^ sw)];
            af[mi][1] = *(const short8*)&As[cur][r * 64 + ((32 + lg * 8) ^ sw)];
        }
#pragma unroll
        for (int ni = 0; ni < NI; ++ni) {
            int r = brow[ni], sw = (r & 7) * 8;
            bf[ni][0] = *(const short8*)&Bs[cur][r * 64 + ((lg * 8) ^ sw)];
            bf[ni][1] = *(const short8*)&Bs[cur][r * 64 + ((32 + lg * 8) ^ sw)];
        }
#pragma unroll
        for (int kh = 0; kh < 2; ++kh)
#pragma unroll
            for (int mi = 0; mi < MI; ++mi)
#pragma unroll
                for (int ni = 0; ni < NI; ++ni)
                    mfma16x16x32(acc[mi][ni], af[mi][kh], bf[ni][kh]);
        if (t + 1 < T) __syncthreads();
    }

#pragma unroll
    for (int ni = 0; ni < NI; ++ni) {
        int col = bn + wc + ni * 16 + lr;
        float bv = ks ? 0.f : bias[col];
#pragma unroll
        for (int mi = 0; mi < MI; ++mi) {
#pragma unroll
            for (int rr = 0; rr < 4; ++rr) {
                int rowi = bm + wr + mi * 16 + lg * 4 + rr;
                float v = acc[mi][ni][rr] + bv;
                if (relu) v = fmaxf(v, 0.f);
                size_t idx = (size_t)rowi * N + col;
                if (ks) { Cf2[idx] = v; }
                else {
                    if (Cf) Cf[idx] = v;
                    if (Cb) Cb[idx] = f2bf(v);
                }
            }
        }
    }
}

// ---------------------------------------------------------------------------
// MFMA flash attention, fused QKV input [4096][1536]. 512 threads = 8 waves,
// each wave 16 q-rows (QBLK=128). KVBLK=128 staged in LDS (K row-major padded,
// V transposed pair-packed); next chunk reg-prefetched during compute.
// exp2-domain softmax: Q pre-scaled by 0.125*log2(e), P = exp2(S - mx).
// Defer-max (THR=11.54 = 8*log2e): skip max-shuffles + O-rescale while the
// per-tile max stays close (P bounded by 2^11.54; fp32 headroom fine).
// Per-lane denominator: dn kept as lane partials, reduced once in epilogue.
// ---------------------------------------------------------------------------
__global__ __launch_bounds__(512) void attn_mfma(const ushort* __restrict__ QKV,
                                                 ushort* __restrict__ CTX) {
    __shared__ ushort Ks[128][72];
    __shared__ ushort VsT[64][136];
    __shared__ ushort Ps[8][16][136];

    int raw = blockIdx.x;
    int bid = (raw & 7) * 32 + (raw >> 3);   // XCD co-locate (grid=256)
    int qt = bid & 15;             // 16 q-tiles of 128 rows
    int hh = (bid >> 4) & 7;
    int bb = bid >> 7;
    int q0 = qt * 128;
    int tid = threadIdx.x;
    int w = tid >> 6, l = tid & 63;
    int c = l & 15, g = l >> 4;

    size_t qbase = (size_t)bb * SS * QS + hh * DHH;
    size_t kbase = qbase + 512;
    size_t vbase = qbase + 1024;
    size_t obase = (size_t)bb * SS * DD + hh * DHH;

    // Q fragments, scaled by 0.125*log2(e) (exp2-domain scores)
    short8 qf[2];
    {
        const ushort* qp = QKV + qbase + (size_t)(q0 + w * 16 + c) * QS + g * 8;
        short8 q0v = *(const short8*)qp;
        short8 q1v = *(const short8*)(qp + 32);
#pragma unroll
        for (int j = 0; j < 8; ++j) {
            q0v[j] = (short)f2bf(bf2f((unsigned short)q0v[j]) * 0.1803368801f);
            q1v[j] = (short)f2bf(bf2f((unsigned short)q1v[j]) * 0.1803368801f);
        }
        qf[0] = q0v; qf[1] = q1v;
    }

    // K prefetch: row kk = tid>>2 (0..127), 16 dims at (tid&3)*16
    int kk = tid >> 2, kd0 = (tid & 3) * 16;
    // V prefetch: key pair kp = (tid&63)*2, 8 dims at (tid>>6)*8
    int kp = (tid & 63) * 2, dv = (tid >> 6) * 8;

    short8 kreg[2], vreg[2];
    {
        const short8* gk = (const short8*)(QKV + kbase + (size_t)kk * QS + kd0);
        kreg[0] = gk[0]; kreg[1] = gk[1];
        vreg[0] = *(const short8*)(QKV + vbase + (size_t)kp * QS + dv);
        vreg[1] = *(const short8*)(QKV + vbase + (size_t)(kp + 1) * QS + dv);
    }

    floatx4 O[4] = {};
    float mx[4] = {-1e30f, -1e30f, -1e30f, -1e30f};
    float dn[4] = {};   // per-lane partials (group-reduced once at the end)

    for (int ch = 0; ch < SS; ch += 128) {
        __syncthreads();    // prev chunk's readers done; prefetch loads drained
        *(short8*)&Ks[kk][kd0]     = kreg[0];
        *(short8*)&Ks[kk][kd0 + 8] = kreg[1];
#pragma unroll
        for (int j = 0; j < 8; ++j) {
            unsigned int lo = (unsigned short)vreg[0][j], hi = (unsigned short)vreg[1][j];
            *(unsigned int*)&VsT[dv + j][kp] = lo | (hi << 16);
        }
        __syncthreads();    // Ks/VsT ready

        // prefetch next chunk into regs (lands during compute below)
        if (ch + 128 < SS) {
            const short8* gk = (const short8*)(QKV + kbase + (size_t)(ch + 128 + kk) * QS + kd0);
            kreg[0] = gk[0]; kreg[1] = gk[1];
            vreg[0] = *(const short8*)(QKV + vbase + (size_t)(ch + 128 + kp) * QS + dv);
            vreg[1] = *(const short8*)(QKV + vbase + (size_t)(ch + 128 + kp + 1) * QS + dv);
        }

        // QK^T: 16q x 128k per wave (8 key-tiles); scores in log2 domain
        floatx4 S[8];
        __builtin_amdgcn_s_setprio(1);
#pragma unroll
        for (int t = 0; t < 8; ++t) {
            floatx4 z = {};
            short8 k0 = *(const short8*)&Ks[t * 16 + c][g * 8];
            short8 k1 = *(const short8*)&Ks[t * 16 + c][32 + g * 8];
            mfma16x16x32(z, qf[0], k0);
            mfma16x16x32(z, qf[1], k1);
            S[t] = z;
        }
        __builtin_amdgcn_s_setprio(0);

        // online softmax, exp2 domain, defer-max, per-lane dn
#pragma unroll
        for (int r = 0; r < 4; ++r) {
            float pml = fmaxf(fmaxf(fmaxf(S[0][r], S[1][r]), fmaxf(S[2][r], S[3][r])),
                              fmaxf(fmaxf(S[4][r], S[5][r]), fmaxf(S[6][r], S[7][r])));
            if (!__all(pml - mx[r] <= 11.54f)) {
                float pm = pml;
                pm = fmaxf(pm, __shfl_xor(pm, 1));
                pm = fmaxf(pm, __shfl_xor(pm, 2));
                pm = fmaxf(pm, __shfl_xor(pm, 4));
                pm = fmaxf(pm, __shfl_xor(pm, 8));
                float nmr = fmaxf(mx[r], pm);
                float scr = EXP2F(mx[r] - nmr);
                dn[r] *= scr;
                O[0][r] *= scr; O[1][r] *= scr; O[2][r] *= scr; O[3][r] *= scr;
                mx[r] = nmr;
            }
            float e[8];
            float ps = 0.f;
#pragma unroll
            for (int t = 0; t < 8; ++t) {
                e[t] = EXP2F(S[t][r] - mx[r]);
                ps += e[t];
            }
            dn[r] += ps;    // lane-partial; no per-chunk cross-lane reduce
            int q = 4 * g + r;
#pragma unroll
            for (int t = 0; t < 8; ++t)
                Ps[w][q][t * 16 + c] = f2bf_fast(e[t]);
        }

        // PV: O += P(16q x 128k) . V(128k x 64d)
        __builtin_amdgcn_s_setprio(1);
#pragma unroll
        for (int s = 0; s < 4; ++s) {
            short8 pa = *(const short8*)&Ps[w][c][s * 32 + g * 8];
#pragma unroll
            for (int dt = 0; dt < 4; ++dt) {
                short8 vb = *(const short8*)&VsT[dt * 16 + c][s * 32 + g * 8];
                mfma16x16x32(O[dt], pa, vb);
            }
        }
        __builtin_amdgcn_s_setprio(0);
    }

    // epilogue: reduce dn across the 16-lane key groups, then normalize
    float inv[4];
#pragma unroll
    for (int r = 0; r < 4; ++r) {
        float d = dn[r];
        d += __shfl_xor(d, 1);
        d += __shfl_xor(d, 2);
        d += __shfl_xor(d, 4);
        d += __shfl_xor(d, 8);
        inv[r] = 1.f / d;
    }
#pragma unroll
    for (int dt = 0; dt < 4; ++dt) {
#pragma unroll
        for (int r = 0; r < 4; ++r) {
            size_t op = obase + (size_t)(q0 + w * 16 + 4 * g + r) * DD + dt * 16 + c;
            CTX[op] = f2bf(O[dt][r] * inv[r]);
        }
    }
}

// ---------------------------------------------------------------------------
// hout = LayerNorm(hin + yin [+ y2]) * g + b. 256 threads = 2 rows/block,
// float4 loads, single-pass mean/var. Optional bf16 copy.
// ---------------------------------------------------------------------------
__global__ __launch_bounds__(256) void add_ln(const float* __restrict__ hin,
                                              const float* __restrict__ yin,
                                              const float* __restrict__ y2,
                                              const float* __restrict__ g,
                                              const float* __restrict__ b,
                                              float* __restrict__ hout,
                                              ushort* __restrict__ bout) {
    __shared__ float shs[2][2], shq[2][2];
    int rh = threadIdx.x >> 7;          // row half: 0..1
    int t  = threadIdx.x & 127;         // 0..127
    int wv = (threadIdx.x >> 6) & 1;    // wave within row group
    int row = blockIdx.x * 2 + rh;
    const float4 hv = ((const float4*)(hin + (size_t)row * DD))[t];
    const float4 yv = ((const float4*)(yin + (size_t)row * DD))[t];
    float4 v;
    v.x = hv.x + yv.x; v.y = hv.y + yv.y; v.z = hv.z + yv.z; v.w = hv.w + yv.w;
    if (y2) {
        const float4 y2v = ((const float4*)(y2 + (size_t)row * DD))[t];
        v.x += y2v.x; v.y += y2v.y; v.z += y2v.z; v.w += y2v.w;
    }
    float s = v.x + v.y + v.z + v.w;
    float q = v.x * v.x + v.y * v.y + v.z * v.z + v.w * v.w;
#pragma unroll
    for (int off = 32; off; off >>= 1) {
        s += __shfl_xor(s, off);
        q += __shfl_xor(q, off);
    }
    if ((threadIdx.x & 63) == 0) { shs[rh][wv] = s; shq[rh][wv] = q; }
    __syncthreads();
    float St = shs[rh][0] + shs[rh][1], Qt = shq[rh][0] + shq[rh][1];
    float mean = St * (1.f / 512.f);
    float var = Qt * (1.f / 512.f) - mean * mean;
    float rstd = rsqrtf(var + 1e-5f);
    const float4 gv = ((const float4*)g)[t];
    const float4 bv = ((const float4*)b)[t];
    float4 r;
    r.x = (v.x - mean) * rstd * gv.x + bv.x;
    r.y = (v.y - mean) * rstd * gv.y + bv.y;
    r.z = (v.z - mean) * rstd * gv.z + bv.z;
    r.w = (v.w - mean) * rstd * gv.w + bv.w;
    ((float4*)(hout + (size_t)row * DD))[t] = r;
    if (bout) {
        union { ushort u[4]; unsigned long long ll; } pk;
        pk.u[0] = f2bf(r.x); pk.u[1] = f2bf(r.y);
        pk.u[2] = f2bf(r.z); pk.u[3] = f2bf(r.w);
        *(unsigned long long*)(bout + (size_t)row * DD + t * 4) = pk.ll;
    }
}

// ---------------------------------------------------------------------------
extern "C" void kernel_launch(void* const* d_in, const int* in_sizes, int n_in,
                              void* d_out, int out_size, void* d_ws, size_t ws_size,
                              hipStream_t stream) {
    const int*   x    = (const int*)d_in[0];
    const float* emb  = (const float*)d_in[1];
    const float* Wq   = (const float*)d_in[2];
    const float* bq   = (const float*)d_in[3];
    const float* Wk   = (const float*)d_in[4];
    const float* bk   = (const float*)d_in[5];
    const float* Wv   = (const float*)d_in[6];
    const float* bv   = (const float*)d_in[7];
    const float* Wo   = (const float*)d_in[8];
    const float* bo   = (const float*)d_in[9];
    const float* W1   = (const float*)d_in[10];
    const float* b1   = (const float*)d_in[11];
    const float* W2   = (const float*)d_in[12];
    const float* b2   = (const float*)d_in[13];
    const float* g1   = (const float*)d_in[14];
    const float* be1  = (const float*)d_in[15];
    const float* g2   = (const float*)d_in[16];
    const float* be2  = (const float*)d_in[17];
    float* out = (float*)d_out;

    char* ws = (char*)d_ws;
    size_t off = 0;
    auto alloc = [&](size_t bytes) -> void* {
        void* p = ws + off;
        off += (bytes + 255) & ~(size_t)255;
        return p;
    };
    float*  h    = (float*)alloc((size_t)NROWS * DD * 4);
    float*  y    = (float*)alloc((size_t)NROWS * DD * 4);
    float*  y2   = (float*)alloc((size_t)NROWS * DD * 4);
    ushort* hb   = (ushort*)alloc((size_t)NROWS * DD * 2);
    ushort* qkv  = (ushort*)alloc((size_t)NROWS * QS * 2);   // 12MB
    ushort* ctxb = (ushort*)alloc((size_t)NROWS * DD * 2);   // 4MB (adjacent)
    ushort* ff1  = qkv;   // FF1 [4096][2048] aliases dead qkv+ctxb (16MB)
    ushort* qkvT = (ushort*)alloc((size_t)6 * QS * DD * 2);
    ushort* WoT  = (ushort*)alloc((size_t)6 * DD * DD * 2);
    ushort* W1T  = (ushort*)alloc((size_t)6 * DD * 2048 * 2);
    ushort* W2T  = (ushort*)alloc((size_t)6 * DD * 2048 * 2);
    float*  qkvB = (float*)alloc((size_t)6 * QS * 4);

    if (ws_size < off) return;   // diagnostic guard (zeros signature)

    dim3 tb(32, 8);
    transpose_k<<<dim3(16, 16, 6), tb, 0, stream>>>(Wq, qkvT,              512, 512, QS * DD);
    transpose_k<<<dim3(16, 16, 6), tb, 0, stream>>>(Wk, qkvT + 512 * DD,   512, 512, QS * DD);
    transpose_k<<<dim3(16, 16, 6), tb, 0, stream>>>(Wv, qkvT + 1024 * DD,  512, 512, QS * DD);
    transpose_k<<<dim3(16, 16, 6), tb, 0, stream>>>(Wo, WoT,               512, 512, DD * DD);
    transpose_k<<<dim3(64, 16, 6), tb, 0, stream>>>(W1, W1T,  512, 2048, 2048 * DD);
    transpose_k<<<dim3(16, 64, 6), tb, 0, stream>>>(W2, W2T, 2048,  512, 2048 * DD);
    concat_bias<<<6, 512, 0, stream>>>(bq, bk, bv, qkvB);

    embed_pe<<<NROWS, 256, 0, stream>>>(x, emb, h, hb);

    for (int l = 0; l < 6; ++l) {
        gemm128<<<384, 256, 0, stream>>>(hb, qkvT + (size_t)l * QS * DD, qkvB + l * QS,
                                         nullptr, qkv, nullptr, NROWS, QS, 512, 0, 1);
        attn_mfma<<<256, 512, 0, stream>>>(qkv, ctxb);
        gemm128<<<256, 256, 0, stream>>>(ctxb, WoT + (size_t)l * DD * DD, bo + l * DD,
                                         y, nullptr, y2, NROWS, DD, 512, 0, 2);
        add_ln<<<2048, 256, 0, stream>>>(h, y, y2, g1 + l * DD, be1 + l * DD, h, hb);
        gemm128<<<512, 256, 0, stream>>>(hb, W1T + (size_t)l * 2048 * DD, b1 + l * 2048,
                                         nullptr, ff1, nullptr, NROWS, 2048, 512, 1, 1);
        gemm128<<<256, 256, 0, stream>>>(ff1, W2T + (size_t)l * 2048 * DD, b2 + l * DD,
                                         y, nullptr, y2, NROWS, DD, 2048, 0, 2);
        add_ln<<<2048, 256, 0, stream>>>(h, y, y2, g2 + l * DD, be2 + l * DD,
                                         (l == 5) ? out : h, (l == 5) ? nullptr : hb);
    }
}